// Round 10
// baseline (843.681 us; speedup 1.0000x reference)
//
#include <hip/hip_runtime.h>
#include <math.h>

constexpr int HD = 128;     // hidden width per layer
constexpr int DD = 384;     // 3*HD concat
constexpr int KK = 30;      // sort-pool k
constexpr int C1N = 16;
constexpr int C2N = 32;
constexpr int KERN5 = 5;
constexpr int CONVL = 26;   // K - KERN + 1
constexpr int PL = 13;      // pooled length
constexpr int FLAT = 416;   // C2N * PL

// ---------------- degree count ----------------
__global__ void deg_kernel(const int* __restrict__ col, int* __restrict__ cnt, int E) {
  int e = blockIdx.x * blockDim.x + threadIdx.x;
  if (e < E) atomicAdd(&cnt[col[e]], 1);
}

// ---------------- device-wide exclusive scan, 3 kernels (1024 elems/block) ----------------
__global__ void scan1_kernel(const int* __restrict__ cnt, int* __restrict__ bsum, int N) {
  __shared__ int red[256];
  int t = threadIdx.x, b = blockIdx.x;
  int base = b * 1024 + t * 4;
  int s = 0;
#pragma unroll
  for (int j = 0; j < 4; ++j) { int idx = base + j; if (idx < N) s += cnt[idx]; }
  red[t] = s;
  __syncthreads();
  for (int o = 128; o > 0; o >>= 1) { if (t < o) red[t] += red[t + o]; __syncthreads(); }
  if (t == 0) bsum[b] = red[0];
}

__global__ void scan2_kernel(int* __restrict__ bsum, int nb) {
  __shared__ int s[1024];
  int t = threadIdx.x;
  int v = (t < nb) ? bsum[t] : 0;
  s[t] = v;
  __syncthreads();
  for (int o = 1; o < 1024; o <<= 1) {
    int u = (t >= o) ? s[t - o] : 0;
    __syncthreads();
    s[t] += u;
    __syncthreads();
  }
  if (t < nb) bsum[t] = s[t] - v;   // exclusive
}

__global__ void scan3_kernel(const int* __restrict__ cnt, const int* __restrict__ bsum,
                             int* __restrict__ offsets, int N) {
  __shared__ int red[256];
  int t = threadIdx.x, b = blockIdx.x;
  int base = b * 1024 + t * 4;
  int v[4]; int s = 0;
#pragma unroll
  for (int j = 0; j < 4; ++j) { int idx = base + j; v[j] = (idx < N) ? cnt[idx] : 0; s += v[j]; }
  red[t] = s;
  __syncthreads();
  for (int o = 1; o < 256; o <<= 1) {           // Hillis-Steele inclusive
    int u = (t >= o) ? red[t - o] : 0;
    __syncthreads();
    red[t] += u;
    __syncthreads();
  }
  int run = bsum[b] + red[t] - s;               // exclusive prefix for this thread
#pragma unroll
  for (int j = 0; j < 4; ++j) {
    int idx = base + j;
    if (idx < N) {
      offsets[idx] = run;
      run += v[j];
      if (idx == N - 1) offsets[N] = run;
    }
  }
}

// ---------------- dis = 1/sqrt(deg), deg = cnt + 1 (self loop) ----------------
__global__ void dis_kernel(const int* __restrict__ cnt, float* __restrict__ dis, int N) {
  int i = blockIdx.x * blockDim.x + threadIdx.x;
  if (i < N) dis[i] = 1.0f / sqrtf((float)(cnt[i] + 1));
}

// ---------------- CSR fill (incoming edges per node) ----------------
__global__ void fill_kernel(const int* __restrict__ row, const int* __restrict__ col,
                            const int* __restrict__ offsets, int* __restrict__ cursor,
                            int* __restrict__ csr_src, int E) {
  int e = blockIdx.x * blockDim.x + threadIdx.x;
  if (e < E) {
    int c = col[e];
    int p = offsets[c] + atomicAdd(&cursor[c], 1);
    csr_src[p] = row[e];
  }
}

// ---------------- layer 0: x1 = tanh(agg(W0[z]) + b0)  (one wave per node) ----------------
__global__ __launch_bounds__(256) void agg0_kernel(
    const int* __restrict__ z, const int* __restrict__ offsets,
    const int* __restrict__ csr_src, const float* __restrict__ dis,
    const float* __restrict__ W0, const float* __restrict__ b0,
    float* __restrict__ x1, int N) {
  int wid = (blockIdx.x * blockDim.x + threadIdx.x) >> 6;
  int lane = threadIdx.x & 63;
  if (wid >= N) return;
  int i = wid;
  int c0 = lane * 2;
  float di = dis[i];
  int beg = offsets[i], end = offsets[i + 1];
  float ax = 0.f, ay = 0.f;
  int e = beg;
  for (; e + 8 <= end; e += 8) {                 // unroll-8: 8 row-gathers in flight
    int s0 = csr_src[e],     s1 = csr_src[e + 1], s2 = csr_src[e + 2], s3 = csr_src[e + 3];
    int s4 = csr_src[e + 4], s5 = csr_src[e + 5], s6 = csr_src[e + 6], s7 = csr_src[e + 7];
    float w0 = dis[s0], w1 = dis[s1], w2 = dis[s2], w3 = dis[s3];
    float w4 = dis[s4], w5 = dis[s5], w6 = dis[s6], w7 = dis[s7];
    const float2 y0 = *(const float2*)(W0 + (size_t)z[s0] * HD + c0);
    const float2 y1 = *(const float2*)(W0 + (size_t)z[s1] * HD + c0);
    const float2 y2 = *(const float2*)(W0 + (size_t)z[s2] * HD + c0);
    const float2 y3 = *(const float2*)(W0 + (size_t)z[s3] * HD + c0);
    const float2 y4 = *(const float2*)(W0 + (size_t)z[s4] * HD + c0);
    const float2 y5 = *(const float2*)(W0 + (size_t)z[s5] * HD + c0);
    const float2 y6 = *(const float2*)(W0 + (size_t)z[s6] * HD + c0);
    const float2 y7 = *(const float2*)(W0 + (size_t)z[s7] * HD + c0);
    float axa = fmaf(w0, y0.x, fmaf(w1, y1.x, fmaf(w2, y2.x, w3 * y3.x)));
    float axb = fmaf(w4, y4.x, fmaf(w5, y5.x, fmaf(w6, y6.x, w7 * y7.x)));
    float aya = fmaf(w0, y0.y, fmaf(w1, y1.y, fmaf(w2, y2.y, w3 * y3.y)));
    float ayb = fmaf(w4, y4.y, fmaf(w5, y5.y, fmaf(w6, y6.y, w7 * y7.y)));
    ax += axa + axb;
    ay += aya + ayb;
  }
  for (; e + 4 <= end; e += 4) {
    int s0 = csr_src[e], s1 = csr_src[e + 1], s2 = csr_src[e + 2], s3 = csr_src[e + 3];
    float w0 = dis[s0], w1 = dis[s1], w2 = dis[s2], w3 = dis[s3];
    const float2 y0 = *(const float2*)(W0 + (size_t)z[s0] * HD + c0);
    const float2 y1 = *(const float2*)(W0 + (size_t)z[s1] * HD + c0);
    const float2 y2 = *(const float2*)(W0 + (size_t)z[s2] * HD + c0);
    const float2 y3 = *(const float2*)(W0 + (size_t)z[s3] * HD + c0);
    ax = fmaf(w0, y0.x, fmaf(w1, y1.x, fmaf(w2, y2.x, fmaf(w3, y3.x, ax))));
    ay = fmaf(w0, y0.y, fmaf(w1, y1.y, fmaf(w2, y2.y, fmaf(w3, y3.y, ay))));
  }
  for (; e < end; ++e) {
    int s = csr_src[e];
    float w = dis[s];
    const float2 ys = *(const float2*)(W0 + (size_t)z[s] * HD + c0);
    ax = fmaf(w, ys.x, ax);
    ay = fmaf(w, ys.y, ay);
  }
  const float2 yi = *(const float2*)(W0 + (size_t)z[i] * HD + c0);
  float inv = di * di;  // norm of the self-loop exactly
  float ox = tanhf(di * ax + inv * yi.x + b0[c0]);
  float oy = tanhf(di * ay + inv * yi.y + b0[c0 + 1]);
  *(float2*)(x1 + (size_t)i * HD + c0) = make_float2(ox, oy);
}

// ---------------- fused layer: xout = tanh(agg(x) @ W + b) ----------------
// Phase 1 (gather): 4 waves stage the aggregated 64-row tile into LDS.
// Phase 2 (GEMM): 64x128 tile from LDS, bias+tanh epilogue.
// Kills the T intermediate (64 MB write + 64 MB read per layer) entirely.
// LDS 49.4 KB -> 3 blocks/CU; 12 waves x 8 gathers in flight = 48 KB >> Little's-law
// requirement, so the gather stays BW-bound despite lower occupancy.
__global__ __launch_bounds__(256) void fused_layer_kernel(
    const float* __restrict__ x, const int* __restrict__ offsets,
    const int* __restrict__ csr_src, const float* __restrict__ dis,
    const float* __restrict__ W, const float* __restrict__ b,
    float* __restrict__ xout, int N) {
  __shared__ float Xs[64][129];   // +1 pad: A-col reads spread ty groups over 4 banks
  __shared__ float Ws[32][128];
  int t = threadIdx.x;
  int r0 = blockIdx.x * 64;
  int w = t >> 6, lane = t & 63;
  int c0 = lane * 2;

  // ---- gather phase: wave w aggregates nodes r0 + w*16 .. +15 into Xs ----
  for (int it = 0; it < 16; ++it) {
    int li = w * 16 + it;
    int i = r0 + li;
    float di = dis[i];
    int beg = offsets[i], end = offsets[i + 1];
    float ax = 0.f, ay = 0.f;
    int e = beg;
    for (; e + 8 <= end; e += 8) {
      int s0 = csr_src[e],     s1 = csr_src[e + 1], s2 = csr_src[e + 2], s3 = csr_src[e + 3];
      int s4 = csr_src[e + 4], s5 = csr_src[e + 5], s6 = csr_src[e + 6], s7 = csr_src[e + 7];
      float w0 = dis[s0], w1 = dis[s1], w2 = dis[s2], w3 = dis[s3];
      float w4 = dis[s4], w5 = dis[s5], w6 = dis[s6], w7 = dis[s7];
      const float2 y0 = *(const float2*)(x + (size_t)s0 * HD + c0);
      const float2 y1 = *(const float2*)(x + (size_t)s1 * HD + c0);
      const float2 y2 = *(const float2*)(x + (size_t)s2 * HD + c0);
      const float2 y3 = *(const float2*)(x + (size_t)s3 * HD + c0);
      const float2 y4 = *(const float2*)(x + (size_t)s4 * HD + c0);
      const float2 y5 = *(const float2*)(x + (size_t)s5 * HD + c0);
      const float2 y6 = *(const float2*)(x + (size_t)s6 * HD + c0);
      const float2 y7 = *(const float2*)(x + (size_t)s7 * HD + c0);
      float axa = fmaf(w0, y0.x, fmaf(w1, y1.x, fmaf(w2, y2.x, w3 * y3.x)));
      float axb = fmaf(w4, y4.x, fmaf(w5, y5.x, fmaf(w6, y6.x, w7 * y7.x)));
      float aya = fmaf(w0, y0.y, fmaf(w1, y1.y, fmaf(w2, y2.y, w3 * y3.y)));
      float ayb = fmaf(w4, y4.y, fmaf(w5, y5.y, fmaf(w6, y6.y, w7 * y7.y)));
      ax += axa + axb;
      ay += aya + ayb;
    }
    for (; e + 4 <= end; e += 4) {
      int s0 = csr_src[e], s1 = csr_src[e + 1], s2 = csr_src[e + 2], s3 = csr_src[e + 3];
      float w0 = dis[s0], w1 = dis[s1], w2 = dis[s2], w3 = dis[s3];
      const float2 y0 = *(const float2*)(x + (size_t)s0 * HD + c0);
      const float2 y1 = *(const float2*)(x + (size_t)s1 * HD + c0);
      const float2 y2 = *(const float2*)(x + (size_t)s2 * HD + c0);
      const float2 y3 = *(const float2*)(x + (size_t)s3 * HD + c0);
      ax = fmaf(w0, y0.x, fmaf(w1, y1.x, fmaf(w2, y2.x, fmaf(w3, y3.x, ax))));
      ay = fmaf(w0, y0.y, fmaf(w1, y1.y, fmaf(w2, y2.y, fmaf(w3, y3.y, ay))));
    }
    for (; e < end; ++e) {
      int s = csr_src[e];
      float ww = dis[s];
      const float2 xs = *(const float2*)(x + (size_t)s * HD + c0);
      ax = fmaf(ww, xs.x, ax);
      ay = fmaf(ww, xs.y, ay);
    }
    const float2 xi = *(const float2*)(x + (size_t)i * HD + c0);
    float inv = di * di;
    Xs[li][c0]     = di * ax + inv * xi.x;
    Xs[li][c0 + 1] = di * ay + inv * xi.y;
  }

  // ---- GEMM phase: out[r0..r0+63] = tanh(Xs @ W + b) ----
  int ty = t >> 4, tx = t & 15;   // 16x16 thread grid: 4 rows x 8 cols each
  int R0 = ty * 4;
  float acc[4][8];
#pragma unroll
  for (int a = 0; a < 4; ++a)
#pragma unroll
    for (int c = 0; c < 8; ++c) acc[a][c] = 0.f;

  for (int kb = 0; kb < 128; kb += 32) {
    __syncthreads();   // kb=0: gather writes complete; kb>0: Ws no longer in use
    for (int l = t; l < 1024; l += 256) {       // stage 32x128 W tile
      int k = l >> 5, c4 = (l & 31) << 2;
      *(float4*)(&Ws[k][c4]) = *(const float4*)(W + (size_t)(kb + k) * HD + c4);
    }
    __syncthreads();
#pragma unroll
    for (int k = 0; k < 32; ++k) {
      float a0 = Xs[R0 + 0][kb + k];   // 4 banks across ty groups (pad 129), 16-way bcast
      float a1 = Xs[R0 + 1][kb + k];
      float a2 = Xs[R0 + 2][kb + k];
      float a3 = Xs[R0 + 3][kb + k];
      float4 blo = *(const float4*)(&Ws[k][tx * 4]);
      float4 bhi = *(const float4*)(&Ws[k][64 + tx * 4]);
      float bb[8] = {blo.x, blo.y, blo.z, blo.w, bhi.x, bhi.y, bhi.z, bhi.w};
      float aa[4] = {a0, a1, a2, a3};
#pragma unroll
      for (int ri = 0; ri < 4; ++ri)
#pragma unroll
        for (int ci = 0; ci < 8; ++ci)
          acc[ri][ci] = fmaf(aa[ri], bb[ci], acc[ri][ci]);
    }
  }
  float4 bl = *(const float4*)(b + tx * 4);
  float4 bh = *(const float4*)(b + 64 + tx * 4);
#pragma unroll
  for (int ri = 0; ri < 4; ++ri) {
    float4 o0 = make_float4(tanhf(acc[ri][0] + bl.x), tanhf(acc[ri][1] + bl.y),
                            tanhf(acc[ri][2] + bl.z), tanhf(acc[ri][3] + bl.w));
    float4 o1 = make_float4(tanhf(acc[ri][4] + bh.x), tanhf(acc[ri][5] + bh.y),
                            tanhf(acc[ri][6] + bh.z), tanhf(acc[ri][7] + bh.w));
    *(float4*)(xout + (size_t)(r0 + R0 + ri) * HD + tx * 4) = o0;
    *(float4*)(xout + (size_t)(r0 + R0 + ri) * HD + 64 + tx * 4) = o1;
  }
}

// ---------------- per-graph start offsets (batch is sorted) ----------------
__global__ void gstart_kernel(const int* __restrict__ batch, int* __restrict__ gstart,
                              int N, int B) {
  int g = blockIdx.x * blockDim.x + threadIdx.x;
  if (g > B) return;
  int lo = 0, hi = N;
  while (lo < hi) { int mid = (lo + hi) >> 1; if (batch[mid] < g) lo = mid + 1; else hi = mid; }
  gstart[g] = lo;
}

// ---------------- sort-pool + conv head, one block per graph, 512 threads ----------------
__global__ __launch_bounds__(512) void head_kernel(
    const float* __restrict__ X1, const float* __restrict__ X2, const float* __restrict__ X3,
    const int* __restrict__ gstart,
    const float* __restrict__ Wc1, const float* __restrict__ bc1,
    const float* __restrict__ Wc2, const float* __restrict__ bc2,
    const float* __restrict__ g1, const float* __restrict__ be1,
    const float* __restrict__ g2, const float* __restrict__ be2,
    const float* __restrict__ rm1, const float* __restrict__ rv1,
    const float* __restrict__ rm2, const float* __restrict__ rv2,
    const float* __restrict__ Wl1, const float* __restrict__ bl1,
    const float* __restrict__ Wl2, const float* __restrict__ bl2,
    float* __restrict__ out) {
  constexpr int MAXC = 512;    // >30 sigma above mean graph size of 128
  __shared__ float vals[MAXC];
  __shared__ int   sel[KK];
  __shared__ float ph[KK][385];          // 46200 B; region reused after conv1
  __shared__ float h1b[C1N][KK + 1];     // persists conv1 -> conv2
  // overlay into ph's region once ph is dead (after conv1):
  float* h2b  = &ph[0][0];               // [C2N * CONVL] = 832
  float* pp   = &ph[0][0] + 832;         // [FLAT] = 416
  float* part = &ph[0][0] + 1248;        // [512]
  float* l1v  = &ph[0][0] + 1760;        // [128]

  int g = blockIdx.x, t = threadIdx.x;
  int start = gstart[g];
  int count = gstart[g + 1] - start;
  if (count > MAXC) count = MAXC;
  int kk = count < KK ? count : KK;

  // ---- selection by parallel rank counting ----
  // rank_i = #{j: v_j > v_i} + #{j<i: v_j == v_i}  == position in stable
  // lexsort (value desc, index asc). Node with rank r < 30 owns sel[r].
  for (int i = t; i < count; i += 512)
    vals[i] = X3[(size_t)(start + i) * HD + (HD - 1)];
  __syncthreads();
  if (t < count) {
    float vi = vals[t];
    int rank = 0;
    for (int j = 0; j < count; ++j) {
      float vj = vals[j];
      rank += (vj > vi) || (vj == vi && j < t);
    }
    if (rank < KK) sel[rank] = t;
  }
  __syncthreads();

  // gather pooled rows from the three layer buffers (zero-pad short graphs)
  for (int l = t; l < KK * DD; l += 512) {
    int r = l / DD, d = l - r * DD;
    float v = 0.f;
    if (r < kk) {
      size_t n = (size_t)(start + sel[r]);
      v = (d < HD) ? X1[n * HD + d]
        : (d < 2 * HD) ? X2[n * HD + (d - HD)]
                       : X3[n * HD + (d - 2 * HD)];
    }
    ph[r][d] = v;
  }
  __syncthreads();

  // conv1 (kernel=stride=D) + relu + bn1   (480 items, one per thread)
  if (t < C1N * KK) {
    int c = t / KK, k = t - c * KK;
    const float* w = Wc1 + c * DD;
    float s = bc1[c];
    for (int d = 0; d < DD; ++d) s = fmaf(ph[k][d], w[d], s);
    s = fmaxf(s, 0.f);
    float sc = g1[c] * rsqrtf(rv1[c] + 1e-5f);
    h1b[c][k] = (s - rm1[c]) * sc + be1[c];
  }
  __syncthreads();   // conv1 reads of ph complete; ph region reusable below

  // conv2 (kernel 5, valid) + relu + bn2   (832 items)
  for (int l = t; l < C2N * CONVL; l += 512) {
    int o = l / CONVL, tt = l - o * CONVL;
    float s = bc2[o];
    const float* w = Wc2 + o * (C1N * KERN5);
#pragma unroll
    for (int c = 0; c < C1N; ++c)
#pragma unroll
      for (int q = 0; q < KERN5; ++q)
        s = fmaf(h1b[c][tt + q], w[c * KERN5 + q], s);
    s = fmaxf(s, 0.f);
    float sc = g2[o] * rsqrtf(rv2[o] + 1e-5f);
    h2b[o * CONVL + tt] = (s - rm2[o]) * sc + be2[o];
  }
  __syncthreads();

  // maxpool(2,2) + flatten (o-major)
  if (t < FLAT) {
    int o = t / PL, u = t - o * PL;
    pp[t] = fmaxf(h2b[o * CONVL + 2 * u], h2b[o * CONVL + 2 * u + 1]);
  }
  __syncthreads();

  // lin1 + relu, split each 416-dot across 4 threads
  {
    int j = t & 127, h = t >> 7;                 // h in {0..3}
    const int Q = FLAT / 4;                      // 104
    const float* w = Wl1 + (size_t)j * FLAT + h * Q;
    float s = (h == 0) ? bl1[j] : 0.f;
    for (int f = 0; f < Q; ++f) s = fmaf(pp[h * Q + f], w[f], s);
    part[t] = s;
  }
  __syncthreads();
  if (t < 128) l1v[t] = fmaxf(part[t] + part[t + 128] + part[t + 256] + part[t + 384], 0.f);
  __syncthreads();

  // lin2 -> scalar
  if (t < 64) {
    float s = l1v[t] * Wl2[t] + l1v[t + 64] * Wl2[t + 64];
#pragma unroll
    for (int o2 = 32; o2 > 0; o2 >>= 1) s += __shfl_down(s, o2);
    if (t == 0) out[g] = s + bl2[0];
  }
}

extern "C" void kernel_launch(void* const* d_in, const int* in_sizes, int n_in,
                              void* d_out, int out_size, void* d_ws, size_t ws_size,
                              hipStream_t stream) {
  const int*   z    = (const int*)d_in[0];
  const int*   ei   = (const int*)d_in[1];
  const int*   batch= (const int*)d_in[2];
  const float* W0   = (const float*)d_in[3];
  const float* b0   = (const float*)d_in[4];
  const float* W1   = (const float*)d_in[5];
  const float* b1   = (const float*)d_in[6];
  const float* W2   = (const float*)d_in[7];
  const float* b2   = (const float*)d_in[8];
  const float* Wc1  = (const float*)d_in[9];
  const float* bc1  = (const float*)d_in[10];
  const float* Wc2  = (const float*)d_in[11];
  const float* bc2  = (const float*)d_in[12];
  const float* g1   = (const float*)d_in[13];
  const float* be1  = (const float*)d_in[14];
  const float* g2   = (const float*)d_in[15];
  const float* be2  = (const float*)d_in[16];
  const float* Wl1  = (const float*)d_in[17];
  const float* bl1  = (const float*)d_in[18];
  const float* Wl2  = (const float*)d_in[19];
  const float* bl2  = (const float*)d_in[20];
  const float* rm1  = (const float*)d_in[21];
  const float* rv1  = (const float*)d_in[22];
  const float* rm2  = (const float*)d_in[23];
  const float* rv2  = (const float*)d_in[24];

  const int N = in_sizes[0];
  const int E = in_sizes[1] / 2;
  const int B = out_size;
  const int* rowp = ei;       // edge_index[0] = source
  const int* colp = ei + E;   // edge_index[1] = target (aggregation axis)

  // workspace plan: 3x64MB layer buffers + csr 4MB + ~2MB aux  (~198 MiB total)
  char* base = (char*)d_ws;
  size_t off = 0;
  auto alloc = [&](size_t bytes) -> void* {
    void* p = base + off;
    off += (bytes + 255) & ~(size_t)255;
    return p;
  };
  int*   cnt     = (int*)alloc((size_t)N * 4);
  int*   offsets = (int*)alloc(((size_t)N + 1) * 4);
  int*   cursor  = (int*)alloc((size_t)N * 4);
  int*   csr_src = (int*)alloc((size_t)E * 4);
  float* dis     = (float*)alloc((size_t)N * 4);
  int*   gstart  = (int*)alloc(((size_t)B + 1) * 4);
  int*   bsum    = (int*)alloc(1024 * 4);
  float* X1      = (float*)alloc((size_t)N * HD * 4);
  float* X2      = (float*)alloc((size_t)N * HD * 4);
  float* X3      = (float*)alloc((size_t)N * HD * 4);
  (void)ws_size; (void)n_in;

  hipMemsetAsync(cnt, 0, (size_t)N * 4, stream);
  hipMemsetAsync(cursor, 0, (size_t)N * 4, stream);

  const int nb = (N + 1023) / 1024;              // 128 for N=131072 (max 1024)
  deg_kernel<<<(E + 255) / 256, 256, 0, stream>>>(colp, cnt, E);
  scan1_kernel<<<nb, 256, 0, stream>>>(cnt, bsum, N);
  scan2_kernel<<<1, 1024, 0, stream>>>(bsum, nb);
  scan3_kernel<<<nb, 256, 0, stream>>>(cnt, bsum, offsets, N);
  dis_kernel<<<(N + 255) / 256, 256, 0, stream>>>(cnt, dis, N);
  fill_kernel<<<(E + 255) / 256, 256, 0, stream>>>(rowp, colp, offsets, cursor, csr_src, E);

  // layer 0: onehot(z)@W0 == W0[z], fused into aggregation, tanh inside
  agg0_kernel<<<(N + 3) / 4, 256, 0, stream>>>(z, offsets, csr_src, dis, W0, b0, X1, N);
  // layers 1,2: fully fused agg->LDS->GEMM (+bias+tanh); no T intermediate
  fused_layer_kernel<<<N / 64, 256, 0, stream>>>(X1, offsets, csr_src, dis, W1, b1, X2, N);
  fused_layer_kernel<<<N / 64, 256, 0, stream>>>(X2, offsets, csr_src, dis, W2, b2, X3, N);

  gstart_kernel<<<(B + 1 + 255) / 256, 256, 0, stream>>>(batch, gstart, N, B);
  head_kernel<<<B, 512, 0, stream>>>(X1, X2, X3, gstart, Wc1, bc1, Wc2, bc2, g1, be1, g2, be2,
                                     rm1, rv1, rm2, rv2, Wl1, bl1, Wl2, bl2, (float*)d_out);
}

// Round 11
// 726.928 us; speedup vs baseline: 1.1606x; 1.1606x over previous
//
#include <hip/hip_runtime.h>
#include <math.h>

constexpr int HD = 128;     // hidden width per layer
constexpr int DD = 384;     // 3*HD concat
constexpr int KK = 30;      // sort-pool k
constexpr int C1N = 16;
constexpr int C2N = 32;
constexpr int KERN5 = 5;
constexpr int CONVL = 26;   // K - KERN + 1
constexpr int PL = 13;      // pooled length
constexpr int FLAT = 416;   // C2N * PL

// ---------------- degree count ----------------
__global__ void deg_kernel(const int* __restrict__ col, int* __restrict__ cnt, int E) {
  int e = blockIdx.x * blockDim.x + threadIdx.x;
  if (e < E) atomicAdd(&cnt[col[e]], 1);
}

// ---------------- device-wide exclusive scan, 3 kernels (1024 elems/block) ----------------
__global__ void scan1_kernel(const int* __restrict__ cnt, int* __restrict__ bsum, int N) {
  __shared__ int red[256];
  int t = threadIdx.x, b = blockIdx.x;
  int base = b * 1024 + t * 4;
  int s = 0;
#pragma unroll
  for (int j = 0; j < 4; ++j) { int idx = base + j; if (idx < N) s += cnt[idx]; }
  red[t] = s;
  __syncthreads();
  for (int o = 128; o > 0; o >>= 1) { if (t < o) red[t] += red[t + o]; __syncthreads(); }
  if (t == 0) bsum[b] = red[0];
}

__global__ void scan2_kernel(int* __restrict__ bsum, int nb) {
  __shared__ int s[1024];
  int t = threadIdx.x;
  int v = (t < nb) ? bsum[t] : 0;
  s[t] = v;
  __syncthreads();
  for (int o = 1; o < 1024; o <<= 1) {
    int u = (t >= o) ? s[t - o] : 0;
    __syncthreads();
    s[t] += u;
    __syncthreads();
  }
  if (t < nb) bsum[t] = s[t] - v;   // exclusive
}

__global__ void scan3_kernel(const int* __restrict__ cnt, const int* __restrict__ bsum,
                             int* __restrict__ offsets, int N) {
  __shared__ int red[256];
  int t = threadIdx.x, b = blockIdx.x;
  int base = b * 1024 + t * 4;
  int v[4]; int s = 0;
#pragma unroll
  for (int j = 0; j < 4; ++j) { int idx = base + j; v[j] = (idx < N) ? cnt[idx] : 0; s += v[j]; }
  red[t] = s;
  __syncthreads();
  for (int o = 1; o < 256; o <<= 1) {           // Hillis-Steele inclusive
    int u = (t >= o) ? red[t - o] : 0;
    __syncthreads();
    red[t] += u;
    __syncthreads();
  }
  int run = bsum[b] + red[t] - s;               // exclusive prefix for this thread
#pragma unroll
  for (int j = 0; j < 4; ++j) {
    int idx = base + j;
    if (idx < N) {
      offsets[idx] = run;
      run += v[j];
      if (idx == N - 1) offsets[N] = run;
    }
  }
}

// ---------------- dis = 1/sqrt(deg), deg = cnt + 1 (self loop) ----------------
__global__ void dis_kernel(const int* __restrict__ cnt, float* __restrict__ dis, int N) {
  int i = blockIdx.x * blockDim.x + threadIdx.x;
  if (i < N) dis[i] = 1.0f / sqrtf((float)(cnt[i] + 1));
}

// ---------------- CSR fill (incoming edges per node) ----------------
__global__ void fill_kernel(const int* __restrict__ row, const int* __restrict__ col,
                            const int* __restrict__ offsets, int* __restrict__ cursor,
                            int* __restrict__ csr_src, int E) {
  int e = blockIdx.x * blockDim.x + threadIdx.x;
  if (e < E) {
    int c = col[e];
    int p = offsets[c] + atomicAdd(&cursor[c], 1);
    csr_src[p] = row[e];
  }
}

// ---------------- layer 0: x1 = tanh(agg(W0[z]) + b0)  (one wave per node) ----------------
__global__ __launch_bounds__(256) void agg0_kernel(
    const int* __restrict__ z, const int* __restrict__ offsets,
    const int* __restrict__ csr_src, const float* __restrict__ dis,
    const float* __restrict__ W0, const float* __restrict__ b0,
    float* __restrict__ x1, int N) {
  int wid = (blockIdx.x * blockDim.x + threadIdx.x) >> 6;
  int lane = threadIdx.x & 63;
  if (wid >= N) return;
  int i = wid;
  int c0 = lane * 2;
  float di = dis[i];
  int beg = offsets[i], end = offsets[i + 1];
  float ax = 0.f, ay = 0.f;
  int e = beg;
  for (; e + 8 <= end; e += 8) {                 // unroll-8: 8 row-gathers in flight
    int s0 = csr_src[e],     s1 = csr_src[e + 1], s2 = csr_src[e + 2], s3 = csr_src[e + 3];
    int s4 = csr_src[e + 4], s5 = csr_src[e + 5], s6 = csr_src[e + 6], s7 = csr_src[e + 7];
    float w0 = dis[s0], w1 = dis[s1], w2 = dis[s2], w3 = dis[s3];
    float w4 = dis[s4], w5 = dis[s5], w6 = dis[s6], w7 = dis[s7];
    const float2 y0 = *(const float2*)(W0 + (size_t)z[s0] * HD + c0);
    const float2 y1 = *(const float2*)(W0 + (size_t)z[s1] * HD + c0);
    const float2 y2 = *(const float2*)(W0 + (size_t)z[s2] * HD + c0);
    const float2 y3 = *(const float2*)(W0 + (size_t)z[s3] * HD + c0);
    const float2 y4 = *(const float2*)(W0 + (size_t)z[s4] * HD + c0);
    const float2 y5 = *(const float2*)(W0 + (size_t)z[s5] * HD + c0);
    const float2 y6 = *(const float2*)(W0 + (size_t)z[s6] * HD + c0);
    const float2 y7 = *(const float2*)(W0 + (size_t)z[s7] * HD + c0);
    float axa = fmaf(w0, y0.x, fmaf(w1, y1.x, fmaf(w2, y2.x, w3 * y3.x)));
    float axb = fmaf(w4, y4.x, fmaf(w5, y5.x, fmaf(w6, y6.x, w7 * y7.x)));
    float aya = fmaf(w0, y0.y, fmaf(w1, y1.y, fmaf(w2, y2.y, w3 * y3.y)));
    float ayb = fmaf(w4, y4.y, fmaf(w5, y5.y, fmaf(w6, y6.y, w7 * y7.y)));
    ax += axa + axb;
    ay += aya + ayb;
  }
  for (; e + 4 <= end; e += 4) {
    int s0 = csr_src[e], s1 = csr_src[e + 1], s2 = csr_src[e + 2], s3 = csr_src[e + 3];
    float w0 = dis[s0], w1 = dis[s1], w2 = dis[s2], w3 = dis[s3];
    const float2 y0 = *(const float2*)(W0 + (size_t)z[s0] * HD + c0);
    const float2 y1 = *(const float2*)(W0 + (size_t)z[s1] * HD + c0);
    const float2 y2 = *(const float2*)(W0 + (size_t)z[s2] * HD + c0);
    const float2 y3 = *(const float2*)(W0 + (size_t)z[s3] * HD + c0);
    ax = fmaf(w0, y0.x, fmaf(w1, y1.x, fmaf(w2, y2.x, fmaf(w3, y3.x, ax))));
    ay = fmaf(w0, y0.y, fmaf(w1, y1.y, fmaf(w2, y2.y, fmaf(w3, y3.y, ay))));
  }
  for (; e < end; ++e) {
    int s = csr_src[e];
    float w = dis[s];
    const float2 ys = *(const float2*)(W0 + (size_t)z[s] * HD + c0);
    ax = fmaf(w, ys.x, ax);
    ay = fmaf(w, ys.y, ay);
  }
  const float2 yi = *(const float2*)(W0 + (size_t)z[i] * HD + c0);
  float inv = di * di;  // norm of the self-loop exactly
  float ox = tanhf(di * ax + inv * yi.x + b0[c0]);
  float oy = tanhf(di * ay + inv * yi.y + b0[c0 + 1]);
  *(float2*)(x1 + (size_t)i * HD + c0) = make_float2(ox, oy);
}

// ---------------- pure aggregation, HALF-WAVE per node ----------------
// 32 lanes x float4 cover the 512B row -> each wave processes 2 nodes concurrently,
// doubling rows-in-flight per wave (16 vs 8) at the same occupancy. Divergence cost
// E[max(d1,d2)] ~ +25% iters vs 2x concurrency.
__global__ __launch_bounds__(256) void agg_kernel(
    const float* __restrict__ x, const int* __restrict__ offsets,
    const int* __restrict__ csr_src, const float* __restrict__ dis,
    float* __restrict__ T, int N) {
  int hw = (blockIdx.x * blockDim.x + threadIdx.x) >> 5;   // half-wave id = node id
  int lane = threadIdx.x & 31;
  if (hw >= N) return;
  int i = hw;
  int c0 = lane * 4;
  float di = dis[i];
  int beg = offsets[i], end = offsets[i + 1];
  float ax = 0.f, ay = 0.f, az = 0.f, aw = 0.f;
  int e = beg;
  for (; e + 8 <= end; e += 8) {                 // 8 float4 row-gathers in flight
    int s0 = csr_src[e],     s1 = csr_src[e + 1], s2 = csr_src[e + 2], s3 = csr_src[e + 3];
    int s4 = csr_src[e + 4], s5 = csr_src[e + 5], s6 = csr_src[e + 6], s7 = csr_src[e + 7];
    float w0 = dis[s0], w1 = dis[s1], w2 = dis[s2], w3 = dis[s3];
    float w4 = dis[s4], w5 = dis[s5], w6 = dis[s6], w7 = dis[s7];
    const float4 y0 = *(const float4*)(x + (size_t)s0 * HD + c0);
    const float4 y1 = *(const float4*)(x + (size_t)s1 * HD + c0);
    const float4 y2 = *(const float4*)(x + (size_t)s2 * HD + c0);
    const float4 y3 = *(const float4*)(x + (size_t)s3 * HD + c0);
    const float4 y4 = *(const float4*)(x + (size_t)s4 * HD + c0);
    const float4 y5 = *(const float4*)(x + (size_t)s5 * HD + c0);
    const float4 y6 = *(const float4*)(x + (size_t)s6 * HD + c0);
    const float4 y7 = *(const float4*)(x + (size_t)s7 * HD + c0);
    ax = fmaf(w0, y0.x, fmaf(w1, y1.x, fmaf(w2, y2.x, fmaf(w3, y3.x, ax))));
    ay = fmaf(w0, y0.y, fmaf(w1, y1.y, fmaf(w2, y2.y, fmaf(w3, y3.y, ay))));
    az = fmaf(w0, y0.z, fmaf(w1, y1.z, fmaf(w2, y2.z, fmaf(w3, y3.z, az))));
    aw = fmaf(w0, y0.w, fmaf(w1, y1.w, fmaf(w2, y2.w, fmaf(w3, y3.w, aw))));
    ax = fmaf(w4, y4.x, fmaf(w5, y5.x, fmaf(w6, y6.x, fmaf(w7, y7.x, ax))));
    ay = fmaf(w4, y4.y, fmaf(w5, y5.y, fmaf(w6, y6.y, fmaf(w7, y7.y, ay))));
    az = fmaf(w4, y4.z, fmaf(w5, y5.z, fmaf(w6, y6.z, fmaf(w7, y7.z, az))));
    aw = fmaf(w4, y4.w, fmaf(w5, y5.w, fmaf(w6, y6.w, fmaf(w7, y7.w, aw))));
  }
  for (; e + 4 <= end; e += 4) {
    int s0 = csr_src[e], s1 = csr_src[e + 1], s2 = csr_src[e + 2], s3 = csr_src[e + 3];
    float w0 = dis[s0], w1 = dis[s1], w2 = dis[s2], w3 = dis[s3];
    const float4 y0 = *(const float4*)(x + (size_t)s0 * HD + c0);
    const float4 y1 = *(const float4*)(x + (size_t)s1 * HD + c0);
    const float4 y2 = *(const float4*)(x + (size_t)s2 * HD + c0);
    const float4 y3 = *(const float4*)(x + (size_t)s3 * HD + c0);
    ax = fmaf(w0, y0.x, fmaf(w1, y1.x, fmaf(w2, y2.x, fmaf(w3, y3.x, ax))));
    ay = fmaf(w0, y0.y, fmaf(w1, y1.y, fmaf(w2, y2.y, fmaf(w3, y3.y, ay))));
    az = fmaf(w0, y0.z, fmaf(w1, y1.z, fmaf(w2, y2.z, fmaf(w3, y3.z, az))));
    aw = fmaf(w0, y0.w, fmaf(w1, y1.w, fmaf(w2, y2.w, fmaf(w3, y3.w, aw))));
  }
  for (; e < end; ++e) {
    int s = csr_src[e];
    float w = dis[s];
    const float4 ys = *(const float4*)(x + (size_t)s * HD + c0);
    ax = fmaf(w, ys.x, ax);
    ay = fmaf(w, ys.y, ay);
    az = fmaf(w, ys.z, az);
    aw = fmaf(w, ys.w, aw);
  }
  const float4 xi = *(const float4*)(x + (size_t)i * HD + c0);
  float inv = di * di;
  float4 o = make_float4(di * ax + inv * xi.x, di * ay + inv * xi.y,
                         di * az + inv * xi.z, di * aw + inv * xi.w);
  *(float4*)(T + (size_t)i * HD + c0) = o;
}

// ---------------- in-place f32 GEMM: T = tanh(T @ W + b), T[N,128], W[128,128] ----------------
__global__ __launch_bounds__(256) void gemm_kernel(
    float* __restrict__ T, const float* __restrict__ W, const float* __restrict__ b, int N) {
  __shared__ float Xs[128][33];   // +1 pad
  __shared__ float Ws[32][128];   // float4 reads at 16B lane stride -> conflict-free
  int t = threadIdx.x;
  int r0 = blockIdx.x * 128;
  int ty = t >> 4, tx = t & 15;
  int R0 = ty * 8;
  float acc[8][8];
#pragma unroll
  for (int a = 0; a < 8; ++a)
#pragma unroll
    for (int c = 0; c < 8; ++c) acc[a][c] = 0.f;

  for (int kb = 0; kb < 128; kb += 32) {
    __syncthreads();
    for (int l = t; l < 1024; l += 256) {       // 128 rows x 8 float4
      int r = l >> 3, c4 = (l & 7) << 2;
      float4 v = *(const float4*)(T + (size_t)(r0 + r) * HD + kb + c4);
      Xs[r][c4] = v.x; Xs[r][c4 + 1] = v.y; Xs[r][c4 + 2] = v.z; Xs[r][c4 + 3] = v.w;
    }
    for (int l = t; l < 1024; l += 256) {       // 32 rows x 32 float4
      int k = l >> 5, c4 = (l & 31) << 2;
      *(float4*)(&Ws[k][c4]) = *(const float4*)(W + (size_t)(kb + k) * HD + c4);
    }
    __syncthreads();
#pragma unroll
    for (int k = 0; k < 32; ++k) {
      float a[8];
#pragma unroll
      for (int ri = 0; ri < 8; ++ri) a[ri] = Xs[R0 + ri][k];
      float4 blo = *(const float4*)(&Ws[k][tx * 4]);
      float4 bhi = *(const float4*)(&Ws[k][64 + tx * 4]);
      float bb[8] = {blo.x, blo.y, blo.z, blo.w, bhi.x, bhi.y, bhi.z, bhi.w};
#pragma unroll
      for (int ri = 0; ri < 8; ++ri)
#pragma unroll
        for (int ci = 0; ci < 8; ++ci)
          acc[ri][ci] = fmaf(a[ri], bb[ci], acc[ri][ci]);
    }
  }
  float4 bl = *(const float4*)(b + tx * 4);
  float4 bh = *(const float4*)(b + 64 + tx * 4);
#pragma unroll
  for (int ri = 0; ri < 8; ++ri) {
    float4 o0 = make_float4(tanhf(acc[ri][0] + bl.x), tanhf(acc[ri][1] + bl.y),
                            tanhf(acc[ri][2] + bl.z), tanhf(acc[ri][3] + bl.w));
    float4 o1 = make_float4(tanhf(acc[ri][4] + bh.x), tanhf(acc[ri][5] + bh.y),
                            tanhf(acc[ri][6] + bh.z), tanhf(acc[ri][7] + bh.w));
    *(float4*)(T + (size_t)(r0 + R0 + ri) * HD + tx * 4) = o0;
    *(float4*)(T + (size_t)(r0 + R0 + ri) * HD + 64 + tx * 4) = o1;
  }
}

// ---------------- per-graph start offsets (batch is sorted) ----------------
__global__ void gstart_kernel(const int* __restrict__ batch, int* __restrict__ gstart,
                              int N, int B) {
  int g = blockIdx.x * blockDim.x + threadIdx.x;
  if (g > B) return;
  int lo = 0, hi = N;
  while (lo < hi) { int mid = (lo + hi) >> 1; if (batch[mid] < g) lo = mid + 1; else hi = mid; }
  gstart[g] = lo;
}

// ---------------- sort-pool + conv head, one block per graph, 512 threads ----------------
__global__ __launch_bounds__(512) void head_kernel(
    const float* __restrict__ X1, const float* __restrict__ X2, const float* __restrict__ X3,
    const int* __restrict__ gstart,
    const float* __restrict__ Wc1, const float* __restrict__ bc1,
    const float* __restrict__ Wc2, const float* __restrict__ bc2,
    const float* __restrict__ g1, const float* __restrict__ be1,
    const float* __restrict__ g2, const float* __restrict__ be2,
    const float* __restrict__ rm1, const float* __restrict__ rv1,
    const float* __restrict__ rm2, const float* __restrict__ rv2,
    const float* __restrict__ Wl1, const float* __restrict__ bl1,
    const float* __restrict__ Wl2, const float* __restrict__ bl2,
    float* __restrict__ out) {
  constexpr int MAXC = 512;    // >30 sigma above mean graph size of 128
  __shared__ float vals[MAXC];
  __shared__ int   sel[KK];
  __shared__ float ph[KK][385];          // 46200 B; region reused after conv1
  __shared__ float h1b[C1N][KK + 1];     // persists conv1 -> conv2
  // overlay into ph's region once ph is dead (after conv1):
  float* h2b  = &ph[0][0];               // [C2N * CONVL] = 832
  float* pp   = &ph[0][0] + 832;         // [FLAT] = 416
  float* part = &ph[0][0] + 1248;        // [512]
  float* l1v  = &ph[0][0] + 1760;        // [128]

  int g = blockIdx.x, t = threadIdx.x;
  int start = gstart[g];
  int count = gstart[g + 1] - start;
  if (count > MAXC) count = MAXC;
  int kk = count < KK ? count : KK;

  // ---- selection by parallel rank counting ----
  for (int i = t; i < count; i += 512)
    vals[i] = X3[(size_t)(start + i) * HD + (HD - 1)];
  __syncthreads();
  if (t < count) {
    float vi = vals[t];
    int rank = 0;
    for (int j = 0; j < count; ++j) {
      float vj = vals[j];
      rank += (vj > vi) || (vj == vi && j < t);
    }
    if (rank < KK) sel[rank] = t;
  }
  __syncthreads();

  // gather pooled rows from the three layer buffers (zero-pad short graphs)
  for (int l = t; l < KK * DD; l += 512) {
    int r = l / DD, d = l - r * DD;
    float v = 0.f;
    if (r < kk) {
      size_t n = (size_t)(start + sel[r]);
      v = (d < HD) ? X1[n * HD + d]
        : (d < 2 * HD) ? X2[n * HD + (d - HD)]
                       : X3[n * HD + (d - 2 * HD)];
    }
    ph[r][d] = v;
  }
  __syncthreads();

  // conv1 (kernel=stride=D) + relu + bn1   (480 items, one per thread)
  if (t < C1N * KK) {
    int c = t / KK, k = t - c * KK;
    const float* w = Wc1 + c * DD;
    float s = bc1[c];
    for (int d = 0; d < DD; ++d) s = fmaf(ph[k][d], w[d], s);
    s = fmaxf(s, 0.f);
    float sc = g1[c] * rsqrtf(rv1[c] + 1e-5f);
    h1b[c][k] = (s - rm1[c]) * sc + be1[c];
  }
  __syncthreads();   // conv1 reads of ph complete; ph region reusable below

  // conv2 (kernel 5, valid) + relu + bn2   (832 items)
  for (int l = t; l < C2N * CONVL; l += 512) {
    int o = l / CONVL, tt = l - o * CONVL;
    float s = bc2[o];
    const float* w = Wc2 + o * (C1N * KERN5);
#pragma unroll
    for (int c = 0; c < C1N; ++c)
#pragma unroll
      for (int q = 0; q < KERN5; ++q)
        s = fmaf(h1b[c][tt + q], w[c * KERN5 + q], s);
    s = fmaxf(s, 0.f);
    float sc = g2[o] * rsqrtf(rv2[o] + 1e-5f);
    h2b[o * CONVL + tt] = (s - rm2[o]) * sc + be2[o];
  }
  __syncthreads();

  // maxpool(2,2) + flatten (o-major)
  if (t < FLAT) {
    int o = t / PL, u = t - o * PL;
    pp[t] = fmaxf(h2b[o * CONVL + 2 * u], h2b[o * CONVL + 2 * u + 1]);
  }
  __syncthreads();

  // lin1 + relu, split each 416-dot across 4 threads
  {
    int j = t & 127, h = t >> 7;                 // h in {0..3}
    const int Q = FLAT / 4;                      // 104
    const float* w = Wl1 + (size_t)j * FLAT + h * Q;
    float s = (h == 0) ? bl1[j] : 0.f;
    for (int f = 0; f < Q; ++f) s = fmaf(pp[h * Q + f], w[f], s);
    part[t] = s;
  }
  __syncthreads();
  if (t < 128) l1v[t] = fmaxf(part[t] + part[t + 128] + part[t + 256] + part[t + 384], 0.f);
  __syncthreads();

  // lin2 -> scalar
  if (t < 64) {
    float s = l1v[t] * Wl2[t] + l1v[t + 64] * Wl2[t + 64];
#pragma unroll
    for (int o2 = 32; o2 > 0; o2 >>= 1) s += __shfl_down(s, o2);
    if (t == 0) out[g] = s + bl2[0];
  }
}

extern "C" void kernel_launch(void* const* d_in, const int* in_sizes, int n_in,
                              void* d_out, int out_size, void* d_ws, size_t ws_size,
                              hipStream_t stream) {
  const int*   z    = (const int*)d_in[0];
  const int*   ei   = (const int*)d_in[1];
  const int*   batch= (const int*)d_in[2];
  const float* W0   = (const float*)d_in[3];
  const float* b0   = (const float*)d_in[4];
  const float* W1   = (const float*)d_in[5];
  const float* b1   = (const float*)d_in[6];
  const float* W2   = (const float*)d_in[7];
  const float* b2   = (const float*)d_in[8];
  const float* Wc1  = (const float*)d_in[9];
  const float* bc1  = (const float*)d_in[10];
  const float* Wc2  = (const float*)d_in[11];
  const float* bc2  = (const float*)d_in[12];
  const float* g1   = (const float*)d_in[13];
  const float* be1  = (const float*)d_in[14];
  const float* g2   = (const float*)d_in[15];
  const float* be2  = (const float*)d_in[16];
  const float* Wl1  = (const float*)d_in[17];
  const float* bl1  = (const float*)d_in[18];
  const float* Wl2  = (const float*)d_in[19];
  const float* bl2  = (const float*)d_in[20];
  const float* rm1  = (const float*)d_in[21];
  const float* rv1  = (const float*)d_in[22];
  const float* rm2  = (const float*)d_in[23];
  const float* rv2  = (const float*)d_in[24];

  const int N = in_sizes[0];
  const int E = in_sizes[1] / 2;
  const int B = out_size;
  const int* rowp = ei;       // edge_index[0] = source
  const int* colp = ei + E;   // edge_index[1] = target (aggregation axis)

  // workspace plan: 3x64MB layer buffers + csr 4MB + ~2MB aux  (~198 MiB total)
  char* base = (char*)d_ws;
  size_t off = 0;
  auto alloc = [&](size_t bytes) -> void* {
    void* p = base + off;
    off += (bytes + 255) & ~(size_t)255;
    return p;
  };
  int*   cnt     = (int*)alloc((size_t)N * 4);
  int*   offsets = (int*)alloc(((size_t)N + 1) * 4);
  int*   cursor  = (int*)alloc((size_t)N * 4);
  int*   csr_src = (int*)alloc((size_t)E * 4);
  float* dis     = (float*)alloc((size_t)N * 4);
  int*   gstart  = (int*)alloc(((size_t)B + 1) * 4);
  int*   bsum    = (int*)alloc(1024 * 4);
  float* X1      = (float*)alloc((size_t)N * HD * 4);
  float* X2      = (float*)alloc((size_t)N * HD * 4);
  float* X3      = (float*)alloc((size_t)N * HD * 4);
  (void)ws_size; (void)n_in;

  hipMemsetAsync(cnt, 0, (size_t)N * 4, stream);
  hipMemsetAsync(cursor, 0, (size_t)N * 4, stream);

  const int nb = (N + 1023) / 1024;              // 128 for N=131072 (max 1024)
  deg_kernel<<<(E + 255) / 256, 256, 0, stream>>>(colp, cnt, E);
  scan1_kernel<<<nb, 256, 0, stream>>>(cnt, bsum, N);
  scan2_kernel<<<1, 1024, 0, stream>>>(bsum, nb);
  scan3_kernel<<<nb, 256, 0, stream>>>(cnt, bsum, offsets, N);
  dis_kernel<<<(N + 255) / 256, 256, 0, stream>>>(cnt, dis, N);
  fill_kernel<<<(E + 255) / 256, 256, 0, stream>>>(rowp, colp, offsets, cursor, csr_src, E);

  // layer 0: onehot(z)@W0 == W0[z], fused into aggregation, tanh inside
  agg0_kernel<<<(N + 3) / 4, 256, 0, stream>>>(z, offsets, csr_src, dis, W0, b0, X1, N);
  // layer 1: aggregate-first (half-wave gather), then in-place GEMM (+bias+tanh)
  agg_kernel<<<N / 8, 256, 0, stream>>>(X1, offsets, csr_src, dis, X2, N);
  gemm_kernel<<<N / 128, 256, 0, stream>>>(X2, W1, b1, N);
  // layer 2
  agg_kernel<<<N / 8, 256, 0, stream>>>(X2, offsets, csr_src, dis, X3, N);
  gemm_kernel<<<N / 128, 256, 0, stream>>>(X3, W2, b2, N);

  gstart_kernel<<<(B + 1 + 255) / 256, 256, 0, stream>>>(batch, gstart, N, B);
  head_kernel<<<B, 512, 0, stream>>>(X1, X2, X3, gstart, Wc1, bc1, Wc2, bc2, g1, be1, g2, be2,
                                     rm1, rv1, rm2, rv2, Wl1, bl1, Wl2, bl2, (float*)d_out);
}

// Round 12
// 725.932 us; speedup vs baseline: 1.1622x; 1.0014x over previous
//
#include <hip/hip_runtime.h>
#include <math.h>

constexpr int HD = 128;     // hidden width per layer
constexpr int DD = 384;     // 3*HD concat
constexpr int KK = 30;      // sort-pool k
constexpr int C1N = 16;
constexpr int C2N = 32;
constexpr int KERN5 = 5;
constexpr int CONVL = 26;   // K - KERN + 1
constexpr int PL = 13;      // pooled length
constexpr int FLAT = 416;   // C2N * PL

// ---------------- degree count ----------------
__global__ void deg_kernel(const int* __restrict__ col, int* __restrict__ cnt, int E) {
  int e = blockIdx.x * blockDim.x + threadIdx.x;
  if (e < E) atomicAdd(&cnt[col[e]], 1);
}

// ---------------- device-wide exclusive scan, 3 kernels (1024 elems/block) ----------------
__global__ void scan1_kernel(const int* __restrict__ cnt, int* __restrict__ bsum, int N) {
  __shared__ int red[256];
  int t = threadIdx.x, b = blockIdx.x;
  int base = b * 1024 + t * 4;
  int s = 0;
#pragma unroll
  for (int j = 0; j < 4; ++j) { int idx = base + j; if (idx < N) s += cnt[idx]; }
  red[t] = s;
  __syncthreads();
  for (int o = 128; o > 0; o >>= 1) { if (t < o) red[t] += red[t + o]; __syncthreads(); }
  if (t == 0) bsum[b] = red[0];
}

__global__ void scan2_kernel(int* __restrict__ bsum, int nb) {
  __shared__ int s[1024];
  int t = threadIdx.x;
  int v = (t < nb) ? bsum[t] : 0;
  s[t] = v;
  __syncthreads();
  for (int o = 1; o < 1024; o <<= 1) {
    int u = (t >= o) ? s[t - o] : 0;
    __syncthreads();
    s[t] += u;
    __syncthreads();
  }
  if (t < nb) bsum[t] = s[t] - v;   // exclusive
}

__global__ void scan3_kernel(const int* __restrict__ cnt, const int* __restrict__ bsum,
                             int* __restrict__ offsets, int N) {
  __shared__ int red[256];
  int t = threadIdx.x, b = blockIdx.x;
  int base = b * 1024 + t * 4;
  int v[4]; int s = 0;
#pragma unroll
  for (int j = 0; j < 4; ++j) { int idx = base + j; v[j] = (idx < N) ? cnt[idx] : 0; s += v[j]; }
  red[t] = s;
  __syncthreads();
  for (int o = 1; o < 256; o <<= 1) {           // Hillis-Steele inclusive
    int u = (t >= o) ? red[t - o] : 0;
    __syncthreads();
    red[t] += u;
    __syncthreads();
  }
  int run = bsum[b] + red[t] - s;               // exclusive prefix for this thread
#pragma unroll
  for (int j = 0; j < 4; ++j) {
    int idx = base + j;
    if (idx < N) {
      offsets[idx] = run;
      run += v[j];
      if (idx == N - 1) offsets[N] = run;
    }
  }
}

// ---------------- dis = 1/sqrt(deg), deg = cnt + 1 (self loop) ----------------
__global__ void dis_kernel(const int* __restrict__ cnt, float* __restrict__ dis, int N) {
  int i = blockIdx.x * blockDim.x + threadIdx.x;
  if (i < N) dis[i] = 1.0f / sqrtf((float)(cnt[i] + 1));
}

// ---------------- CSR fill (incoming edges per node) ----------------
__global__ void fill_kernel(const int* __restrict__ row, const int* __restrict__ col,
                            const int* __restrict__ offsets, int* __restrict__ cursor,
                            int* __restrict__ csr_src, int E) {
  int e = blockIdx.x * blockDim.x + threadIdx.x;
  if (e < E) {
    int c = col[e];
    int p = offsets[c] + atomicAdd(&cursor[c], 1);
    csr_src[p] = row[e];
  }
}

// ---------------- layer 0: x1 = tanh(agg(W0[z]) + b0)  (one wave per node) ----------------
__global__ __launch_bounds__(256) void agg0_kernel(
    const int* __restrict__ z, const int* __restrict__ offsets,
    const int* __restrict__ csr_src, const float* __restrict__ dis,
    const float* __restrict__ W0, const float* __restrict__ b0,
    float* __restrict__ x1, int N) {
  int wid = (blockIdx.x * blockDim.x + threadIdx.x) >> 6;
  int lane = threadIdx.x & 63;
  if (wid >= N) return;
  int i = wid;
  int c0 = lane * 2;
  float di = dis[i];
  int beg = offsets[i], end = offsets[i + 1];
  float ax = 0.f, ay = 0.f;
  int e = beg;
  for (; e + 8 <= end; e += 8) {                 // unroll-8: 8 row-gathers in flight
    int s0 = csr_src[e],     s1 = csr_src[e + 1], s2 = csr_src[e + 2], s3 = csr_src[e + 3];
    int s4 = csr_src[e + 4], s5 = csr_src[e + 5], s6 = csr_src[e + 6], s7 = csr_src[e + 7];
    float w0 = dis[s0], w1 = dis[s1], w2 = dis[s2], w3 = dis[s3];
    float w4 = dis[s4], w5 = dis[s5], w6 = dis[s6], w7 = dis[s7];
    const float2 y0 = *(const float2*)(W0 + (size_t)z[s0] * HD + c0);
    const float2 y1 = *(const float2*)(W0 + (size_t)z[s1] * HD + c0);
    const float2 y2 = *(const float2*)(W0 + (size_t)z[s2] * HD + c0);
    const float2 y3 = *(const float2*)(W0 + (size_t)z[s3] * HD + c0);
    const float2 y4 = *(const float2*)(W0 + (size_t)z[s4] * HD + c0);
    const float2 y5 = *(const float2*)(W0 + (size_t)z[s5] * HD + c0);
    const float2 y6 = *(const float2*)(W0 + (size_t)z[s6] * HD + c0);
    const float2 y7 = *(const float2*)(W0 + (size_t)z[s7] * HD + c0);
    float axa = fmaf(w0, y0.x, fmaf(w1, y1.x, fmaf(w2, y2.x, w3 * y3.x)));
    float axb = fmaf(w4, y4.x, fmaf(w5, y5.x, fmaf(w6, y6.x, w7 * y7.x)));
    float aya = fmaf(w0, y0.y, fmaf(w1, y1.y, fmaf(w2, y2.y, w3 * y3.y)));
    float ayb = fmaf(w4, y4.y, fmaf(w5, y5.y, fmaf(w6, y6.y, w7 * y7.y)));
    ax += axa + axb;
    ay += aya + ayb;
  }
  for (; e + 4 <= end; e += 4) {
    int s0 = csr_src[e], s1 = csr_src[e + 1], s2 = csr_src[e + 2], s3 = csr_src[e + 3];
    float w0 = dis[s0], w1 = dis[s1], w2 = dis[s2], w3 = dis[s3];
    const float2 y0 = *(const float2*)(W0 + (size_t)z[s0] * HD + c0);
    const float2 y1 = *(const float2*)(W0 + (size_t)z[s1] * HD + c0);
    const float2 y2 = *(const float2*)(W0 + (size_t)z[s2] * HD + c0);
    const float2 y3 = *(const float2*)(W0 + (size_t)z[s3] * HD + c0);
    ax = fmaf(w0, y0.x, fmaf(w1, y1.x, fmaf(w2, y2.x, fmaf(w3, y3.x, ax))));
    ay = fmaf(w0, y0.y, fmaf(w1, y1.y, fmaf(w2, y2.y, fmaf(w3, y3.y, ay))));
  }
  for (; e < end; ++e) {
    int s = csr_src[e];
    float w = dis[s];
    const float2 ys = *(const float2*)(W0 + (size_t)z[s] * HD + c0);
    ax = fmaf(w, ys.x, ax);
    ay = fmaf(w, ys.y, ay);
  }
  const float2 yi = *(const float2*)(W0 + (size_t)z[i] * HD + c0);
  float inv = di * di;  // norm of the self-loop exactly
  float ox = tanhf(di * ax + inv * yi.x + b0[c0]);
  float oy = tanhf(di * ay + inv * yi.y + b0[c0 + 1]);
  *(float2*)(x1 + (size_t)i * HD + c0) = make_float2(ox, oy);
}

// ---------------- pure aggregation, HALF-WAVE per node (proven BW-ceiling config) ----------------
__global__ __launch_bounds__(256) void agg_kernel(
    const float* __restrict__ x, const int* __restrict__ offsets,
    const int* __restrict__ csr_src, const float* __restrict__ dis,
    float* __restrict__ T, int N) {
  int hw = (blockIdx.x * blockDim.x + threadIdx.x) >> 5;   // half-wave id = node id
  int lane = threadIdx.x & 31;
  if (hw >= N) return;
  int i = hw;
  int c0 = lane * 4;
  float di = dis[i];
  int beg = offsets[i], end = offsets[i + 1];
  float ax = 0.f, ay = 0.f, az = 0.f, aw = 0.f;
  int e = beg;
  for (; e + 8 <= end; e += 8) {                 // 8 float4 row-gathers in flight
    int s0 = csr_src[e],     s1 = csr_src[e + 1], s2 = csr_src[e + 2], s3 = csr_src[e + 3];
    int s4 = csr_src[e + 4], s5 = csr_src[e + 5], s6 = csr_src[e + 6], s7 = csr_src[e + 7];
    float w0 = dis[s0], w1 = dis[s1], w2 = dis[s2], w3 = dis[s3];
    float w4 = dis[s4], w5 = dis[s5], w6 = dis[s6], w7 = dis[s7];
    const float4 y0 = *(const float4*)(x + (size_t)s0 * HD + c0);
    const float4 y1 = *(const float4*)(x + (size_t)s1 * HD + c0);
    const float4 y2 = *(const float4*)(x + (size_t)s2 * HD + c0);
    const float4 y3 = *(const float4*)(x + (size_t)s3 * HD + c0);
    const float4 y4 = *(const float4*)(x + (size_t)s4 * HD + c0);
    const float4 y5 = *(const float4*)(x + (size_t)s5 * HD + c0);
    const float4 y6 = *(const float4*)(x + (size_t)s6 * HD + c0);
    const float4 y7 = *(const float4*)(x + (size_t)s7 * HD + c0);
    ax = fmaf(w0, y0.x, fmaf(w1, y1.x, fmaf(w2, y2.x, fmaf(w3, y3.x, ax))));
    ay = fmaf(w0, y0.y, fmaf(w1, y1.y, fmaf(w2, y2.y, fmaf(w3, y3.y, ay))));
    az = fmaf(w0, y0.z, fmaf(w1, y1.z, fmaf(w2, y2.z, fmaf(w3, y3.z, az))));
    aw = fmaf(w0, y0.w, fmaf(w1, y1.w, fmaf(w2, y2.w, fmaf(w3, y3.w, aw))));
    ax = fmaf(w4, y4.x, fmaf(w5, y5.x, fmaf(w6, y6.x, fmaf(w7, y7.x, ax))));
    ay = fmaf(w4, y4.y, fmaf(w5, y5.y, fmaf(w6, y6.y, fmaf(w7, y7.y, ay))));
    az = fmaf(w4, y4.z, fmaf(w5, y5.z, fmaf(w6, y6.z, fmaf(w7, y7.z, az))));
    aw = fmaf(w4, y4.w, fmaf(w5, y5.w, fmaf(w6, y6.w, fmaf(w7, y7.w, aw))));
  }
  for (; e + 4 <= end; e += 4) {
    int s0 = csr_src[e], s1 = csr_src[e + 1], s2 = csr_src[e + 2], s3 = csr_src[e + 3];
    float w0 = dis[s0], w1 = dis[s1], w2 = dis[s2], w3 = dis[s3];
    const float4 y0 = *(const float4*)(x + (size_t)s0 * HD + c0);
    const float4 y1 = *(const float4*)(x + (size_t)s1 * HD + c0);
    const float4 y2 = *(const float4*)(x + (size_t)s2 * HD + c0);
    const float4 y3 = *(const float4*)(x + (size_t)s3 * HD + c0);
    ax = fmaf(w0, y0.x, fmaf(w1, y1.x, fmaf(w2, y2.x, fmaf(w3, y3.x, ax))));
    ay = fmaf(w0, y0.y, fmaf(w1, y1.y, fmaf(w2, y2.y, fmaf(w3, y3.y, ay))));
    az = fmaf(w0, y0.z, fmaf(w1, y1.z, fmaf(w2, y2.z, fmaf(w3, y3.z, az))));
    aw = fmaf(w0, y0.w, fmaf(w1, y1.w, fmaf(w2, y2.w, fmaf(w3, y3.w, aw))));
  }
  for (; e < end; ++e) {
    int s = csr_src[e];
    float w = dis[s];
    const float4 ys = *(const float4*)(x + (size_t)s * HD + c0);
    ax = fmaf(w, ys.x, ax);
    ay = fmaf(w, ys.y, ay);
    az = fmaf(w, ys.z, az);
    aw = fmaf(w, ys.w, aw);
  }
  const float4 xi = *(const float4*)(x + (size_t)i * HD + c0);
  float inv = di * di;
  float4 o = make_float4(di * ax + inv * xi.x, di * ay + inv * xi.y,
                         di * az + inv * xi.z, di * aw + inv * xi.w);
  *(float4*)(T + (size_t)i * HD + c0) = o;
}

// ---------------- in-place f32 GEMM: T = tanh(T @ W + b), T[N,128], W[128,128] ----------------
// v2: W read directly from global (64KB, L1/L2-hot; address depends only on (k,tx) ->
// wave touches 16x16B per instr). Kills the Ws LDS stage: LDS 33->17KB (more blocks/CU),
// half the barrier pressure, and the unrolled k-loop pipelines W-loads against FMAs.
__global__ __launch_bounds__(256) void gemm_kernel(
    float* __restrict__ T, const float* __restrict__ W, const float* __restrict__ b, int N) {
  __shared__ float Xs[128][33];   // +1 pad; per-wave A-reads: 4 ty-addrs in 4 distinct banks
  int t = threadIdx.x;
  int r0 = blockIdx.x * 128;
  int ty = t >> 4, tx = t & 15;
  int R0 = ty * 8;
  float acc[8][8];
#pragma unroll
  for (int a = 0; a < 8; ++a)
#pragma unroll
    for (int c = 0; c < 8; ++c) acc[a][c] = 0.f;

  for (int kb = 0; kb < 128; kb += 32) {
    __syncthreads();
    for (int l = t; l < 1024; l += 256) {       // 128 rows x 8 float4
      int r = l >> 3, c4 = (l & 7) << 2;
      float4 v = *(const float4*)(T + (size_t)(r0 + r) * HD + kb + c4);
      Xs[r][c4] = v.x; Xs[r][c4 + 1] = v.y; Xs[r][c4 + 2] = v.z; Xs[r][c4 + 3] = v.w;
    }
    __syncthreads();
#pragma unroll
    for (int k = 0; k < 32; ++k) {
      const float* wr = W + (size_t)(kb + k) * HD;
      float4 blo = *(const float4*)(wr + tx * 4);        // L1/L2-hot global read
      float4 bhi = *(const float4*)(wr + 64 + tx * 4);
      float a[8];
#pragma unroll
      for (int ri = 0; ri < 8; ++ri) a[ri] = Xs[R0 + ri][k];
      float bb[8] = {blo.x, blo.y, blo.z, blo.w, bhi.x, bhi.y, bhi.z, bhi.w};
#pragma unroll
      for (int ri = 0; ri < 8; ++ri)
#pragma unroll
        for (int ci = 0; ci < 8; ++ci)
          acc[ri][ci] = fmaf(a[ri], bb[ci], acc[ri][ci]);
    }
  }
  float4 bl = *(const float4*)(b + tx * 4);
  float4 bh = *(const float4*)(b + 64 + tx * 4);
#pragma unroll
  for (int ri = 0; ri < 8; ++ri) {
    float4 o0 = make_float4(tanhf(acc[ri][0] + bl.x), tanhf(acc[ri][1] + bl.y),
                            tanhf(acc[ri][2] + bl.z), tanhf(acc[ri][3] + bl.w));
    float4 o1 = make_float4(tanhf(acc[ri][4] + bh.x), tanhf(acc[ri][5] + bh.y),
                            tanhf(acc[ri][6] + bh.z), tanhf(acc[ri][7] + bh.w));
    *(float4*)(T + (size_t)(r0 + R0 + ri) * HD + tx * 4) = o0;
    *(float4*)(T + (size_t)(r0 + R0 + ri) * HD + 64 + tx * 4) = o1;
  }
}

// ---------------- per-graph start offsets (batch is sorted) ----------------
__global__ void gstart_kernel(const int* __restrict__ batch, int* __restrict__ gstart,
                              int N, int B) {
  int g = blockIdx.x * blockDim.x + threadIdx.x;
  if (g > B) return;
  int lo = 0, hi = N;
  while (lo < hi) { int mid = (lo + hi) >> 1; if (batch[mid] < g) lo = mid + 1; else hi = mid; }
  gstart[g] = lo;
}

// ---------------- sort-pool + conv head, one block per graph, 512 threads ----------------
__global__ __launch_bounds__(512) void head_kernel(
    const float* __restrict__ X1, const float* __restrict__ X2, const float* __restrict__ X3,
    const int* __restrict__ gstart,
    const float* __restrict__ Wc1, const float* __restrict__ bc1,
    const float* __restrict__ Wc2, const float* __restrict__ bc2,
    const float* __restrict__ g1, const float* __restrict__ be1,
    const float* __restrict__ g2, const float* __restrict__ be2,
    const float* __restrict__ rm1, const float* __restrict__ rv1,
    const float* __restrict__ rm2, const float* __restrict__ rv2,
    const float* __restrict__ Wl1, const float* __restrict__ bl1,
    const float* __restrict__ Wl2, const float* __restrict__ bl2,
    float* __restrict__ out) {
  constexpr int MAXC = 512;    // >30 sigma above mean graph size of 128
  __shared__ float vals[MAXC];
  __shared__ int   sel[KK];
  __shared__ float ph[KK][385];          // 46200 B; region reused after conv1
  __shared__ float h1b[C1N][KK + 1];     // persists conv1 -> conv2
  // overlay into ph's region once ph is dead (after conv1):
  float* h2b  = &ph[0][0];               // [C2N * CONVL] = 832
  float* pp   = &ph[0][0] + 832;         // [FLAT] = 416
  float* part = &ph[0][0] + 1248;        // [512]
  float* l1v  = &ph[0][0] + 1760;        // [128]

  int g = blockIdx.x, t = threadIdx.x;
  int start = gstart[g];
  int count = gstart[g + 1] - start;
  if (count > MAXC) count = MAXC;
  int kk = count < KK ? count : KK;

  // ---- selection by parallel rank counting ----
  for (int i = t; i < count; i += 512)
    vals[i] = X3[(size_t)(start + i) * HD + (HD - 1)];
  __syncthreads();
  if (t < count) {
    float vi = vals[t];
    int rank = 0;
    for (int j = 0; j < count; ++j) {
      float vj = vals[j];
      rank += (vj > vi) || (vj == vi && j < t);
    }
    if (rank < KK) sel[rank] = t;
  }
  __syncthreads();

  // gather pooled rows from the three layer buffers (zero-pad short graphs)
  for (int l = t; l < KK * DD; l += 512) {
    int r = l / DD, d = l - r * DD;
    float v = 0.f;
    if (r < kk) {
      size_t n = (size_t)(start + sel[r]);
      v = (d < HD) ? X1[n * HD + d]
        : (d < 2 * HD) ? X2[n * HD + (d - HD)]
                       : X3[n * HD + (d - 2 * HD)];
    }
    ph[r][d] = v;
  }
  __syncthreads();

  // conv1 (kernel=stride=D) + relu + bn1   (480 items, one per thread)
  if (t < C1N * KK) {
    int c = t / KK, k = t - c * KK;
    const float* w = Wc1 + c * DD;
    float s = bc1[c];
    for (int d = 0; d < DD; ++d) s = fmaf(ph[k][d], w[d], s);
    s = fmaxf(s, 0.f);
    float sc = g1[c] * rsqrtf(rv1[c] + 1e-5f);
    h1b[c][k] = (s - rm1[c]) * sc + be1[c];
  }
  __syncthreads();   // conv1 reads of ph complete; ph region reusable below

  // conv2 (kernel 5, valid) + relu + bn2   (832 items)
  for (int l = t; l < C2N * CONVL; l += 512) {
    int o = l / CONVL, tt = l - o * CONVL;
    float s = bc2[o];
    const float* w = Wc2 + o * (C1N * KERN5);
#pragma unroll
    for (int c = 0; c < C1N; ++c)
#pragma unroll
      for (int q = 0; q < KERN5; ++q)
        s = fmaf(h1b[c][tt + q], w[c * KERN5 + q], s);
    s = fmaxf(s, 0.f);
    float sc = g2[o] * rsqrtf(rv2[o] + 1e-5f);
    h2b[o * CONVL + tt] = (s - rm2[o]) * sc + be2[o];
  }
  __syncthreads();

  // maxpool(2,2) + flatten (o-major)
  if (t < FLAT) {
    int o = t / PL, u = t - o * PL;
    pp[t] = fmaxf(h2b[o * CONVL + 2 * u], h2b[o * CONVL + 2 * u + 1]);
  }
  __syncthreads();

  // lin1 + relu, split each 416-dot across 4 threads
  {
    int j = t & 127, h = t >> 7;                 // h in {0..3}
    const int Q = FLAT / 4;                      // 104
    const float* w = Wl1 + (size_t)j * FLAT + h * Q;
    float s = (h == 0) ? bl1[j] : 0.f;
    for (int f = 0; f < Q; ++f) s = fmaf(pp[h * Q + f], w[f], s);
    part[t] = s;
  }
  __syncthreads();
  if (t < 128) l1v[t] = fmaxf(part[t] + part[t + 128] + part[t + 256] + part[t + 384], 0.f);
  __syncthreads();

  // lin2 -> scalar
  if (t < 64) {
    float s = l1v[t] * Wl2[t] + l1v[t + 64] * Wl2[t + 64];
#pragma unroll
    for (int o2 = 32; o2 > 0; o2 >>= 1) s += __shfl_down(s, o2);
    if (t == 0) out[g] = s + bl2[0];
  }
}

extern "C" void kernel_launch(void* const* d_in, const int* in_sizes, int n_in,
                              void* d_out, int out_size, void* d_ws, size_t ws_size,
                              hipStream_t stream) {
  const int*   z    = (const int*)d_in[0];
  const int*   ei   = (const int*)d_in[1];
  const int*   batch= (const int*)d_in[2];
  const float* W0   = (const float*)d_in[3];
  const float* b0   = (const float*)d_in[4];
  const float* W1   = (const float*)d_in[5];
  const float* b1   = (const float*)d_in[6];
  const float* W2   = (const float*)d_in[7];
  const float* b2   = (const float*)d_in[8];
  const float* Wc1  = (const float*)d_in[9];
  const float* bc1  = (const float*)d_in[10];
  const float* Wc2  = (const float*)d_in[11];
  const float* bc2  = (const float*)d_in[12];
  const float* g1   = (const float*)d_in[13];
  const float* be1  = (const float*)d_in[14];
  const float* g2   = (const float*)d_in[15];
  const float* be2  = (const float*)d_in[16];
  const float* Wl1  = (const float*)d_in[17];
  const float* bl1  = (const float*)d_in[18];
  const float* Wl2  = (const float*)d_in[19];
  const float* bl2  = (const float*)d_in[20];
  const float* rm1  = (const float*)d_in[21];
  const float* rv1  = (const float*)d_in[22];
  const float* rm2  = (const float*)d_in[23];
  const float* rv2  = (const float*)d_in[24];

  const int N = in_sizes[0];
  const int E = in_sizes[1] / 2;
  const int B = out_size;
  const int* rowp = ei;       // edge_index[0] = source
  const int* colp = ei + E;   // edge_index[1] = target (aggregation axis)

  // workspace plan: 3x64MB layer buffers + csr 4MB + ~2MB aux  (~198 MiB total)
  char* base = (char*)d_ws;
  size_t off = 0;
  auto alloc = [&](size_t bytes) -> void* {
    void* p = base + off;
    off += (bytes + 255) & ~(size_t)255;
    return p;
  };
  int*   cnt     = (int*)alloc((size_t)N * 4);
  int*   offsets = (int*)alloc(((size_t)N + 1) * 4);
  int*   cursor  = (int*)alloc((size_t)N * 4);
  int*   csr_src = (int*)alloc((size_t)E * 4);
  float* dis     = (float*)alloc((size_t)N * 4);
  int*   gstart  = (int*)alloc(((size_t)B + 1) * 4);
  int*   bsum    = (int*)alloc(1024 * 4);
  float* X1      = (float*)alloc((size_t)N * HD * 4);
  float* X2      = (float*)alloc((size_t)N * HD * 4);
  float* X3      = (float*)alloc((size_t)N * HD * 4);
  (void)ws_size; (void)n_in;

  hipMemsetAsync(cnt, 0, (size_t)N * 4, stream);
  hipMemsetAsync(cursor, 0, (size_t)N * 4, stream);

  const int nb = (N + 1023) / 1024;              // 128 for N=131072 (max 1024)
  deg_kernel<<<(E + 255) / 256, 256, 0, stream>>>(colp, cnt, E);
  scan1_kernel<<<nb, 256, 0, stream>>>(cnt, bsum, N);
  scan2_kernel<<<1, 1024, 0, stream>>>(bsum, nb);
  scan3_kernel<<<nb, 256, 0, stream>>>(cnt, bsum, offsets, N);
  dis_kernel<<<(N + 255) / 256, 256, 0, stream>>>(cnt, dis, N);
  fill_kernel<<<(E + 255) / 256, 256, 0, stream>>>(rowp, colp, offsets, cursor, csr_src, E);

  // layer 0: onehot(z)@W0 == W0[z], fused into aggregation, tanh inside
  agg0_kernel<<<(N + 3) / 4, 256, 0, stream>>>(z, offsets, csr_src, dis, W0, b0, X1, N);
  // layer 1: aggregate-first (half-wave gather), then in-place GEMM (+bias+tanh)
  agg_kernel<<<N / 8, 256, 0, stream>>>(X1, offsets, csr_src, dis, X2, N);
  gemm_kernel<<<N / 128, 256, 0, stream>>>(X2, W1, b1, N);
  // layer 2
  agg_kernel<<<N / 8, 256, 0, stream>>>(X2, offsets, csr_src, dis, X3, N);
  gemm_kernel<<<N / 128, 256, 0, stream>>>(X3, W2, b2, N);

  gstart_kernel<<<(B + 1 + 255) / 256, 256, 0, stream>>>(batch, gstart, N, B);
  head_kernel<<<B, 512, 0, stream>>>(X1, X2, X3, gstart, Wc1, bc1, Wc2, bc2, g1, be1, g2, be2,
                                     rm1, rv1, rm2, rv2, Wl1, bl1, Wl2, bl2, (float*)d_out);
}

// Round 13
// 684.567 us; speedup vs baseline: 1.2324x; 1.0604x over previous
//
#include <hip/hip_runtime.h>
#include <math.h>

constexpr int HD = 128;     // hidden width per layer
constexpr int DD = 384;     // 3*HD concat
constexpr int KK = 30;      // sort-pool k
constexpr int C1N = 16;
constexpr int C2N = 32;
constexpr int KERN5 = 5;
constexpr int CONVL = 26;   // K - KERN + 1
constexpr int PL = 13;      // pooled length
constexpr int FLAT = 416;   // C2N * PL

// ---------------- degree count ----------------
__global__ void deg_kernel(const int* __restrict__ col, int* __restrict__ cnt, int E) {
  int e = blockIdx.x * blockDim.x + threadIdx.x;
  if (e < E) atomicAdd(&cnt[col[e]], 1);
}

// ---------------- device-wide exclusive scan, 3 kernels (1024 elems/block) ----------------
__global__ void scan1_kernel(const int* __restrict__ cnt, int* __restrict__ bsum, int N) {
  __shared__ int red[256];
  int t = threadIdx.x, b = blockIdx.x;
  int base = b * 1024 + t * 4;
  int s = 0;
#pragma unroll
  for (int j = 0; j < 4; ++j) { int idx = base + j; if (idx < N) s += cnt[idx]; }
  red[t] = s;
  __syncthreads();
  for (int o = 128; o > 0; o >>= 1) { if (t < o) red[t] += red[t + o]; __syncthreads(); }
  if (t == 0) bsum[b] = red[0];
}

__global__ void scan2_kernel(int* __restrict__ bsum, int nb) {
  __shared__ int s[1024];
  int t = threadIdx.x;
  int v = (t < nb) ? bsum[t] : 0;
  s[t] = v;
  __syncthreads();
  for (int o = 1; o < 1024; o <<= 1) {
    int u = (t >= o) ? s[t - o] : 0;
    __syncthreads();
    s[t] += u;
    __syncthreads();
  }
  if (t < nb) bsum[t] = s[t] - v;   // exclusive
}

// scan3 also produces dis[] (dis_kernel folded in: one fewer dispatch)
__global__ void scan3_kernel(const int* __restrict__ cnt, const int* __restrict__ bsum,
                             int* __restrict__ offsets, float* __restrict__ dis, int N) {
  __shared__ int red[256];
  int t = threadIdx.x, b = blockIdx.x;
  int base = b * 1024 + t * 4;
  int v[4]; int s = 0;
#pragma unroll
  for (int j = 0; j < 4; ++j) { int idx = base + j; v[j] = (idx < N) ? cnt[idx] : 0; s += v[j]; }
  red[t] = s;
  __syncthreads();
  for (int o = 1; o < 256; o <<= 1) {           // Hillis-Steele inclusive
    int u = (t >= o) ? red[t - o] : 0;
    __syncthreads();
    red[t] += u;
    __syncthreads();
  }
  int run = bsum[b] + red[t] - s;               // exclusive prefix for this thread
#pragma unroll
  for (int j = 0; j < 4; ++j) {
    int idx = base + j;
    if (idx < N) {
      offsets[idx] = run;
      run += v[j];
      dis[idx] = 1.0f / sqrtf((float)(v[j] + 1));
      if (idx == N - 1) offsets[N] = run;
    }
  }
}

// ---------------- CSR fill (incoming edges per node) ----------------
__global__ void fill_kernel(const int* __restrict__ row, const int* __restrict__ col,
                            const int* __restrict__ offsets, int* __restrict__ cursor,
                            int* __restrict__ csr_src, int E) {
  int e = blockIdx.x * blockDim.x + threadIdx.x;
  if (e < E) {
    int c = col[e];
    int p = offsets[c] + atomicAdd(&cursor[c], 1);
    csr_src[p] = row[e];
  }
}

// ---------------- layer 0: x1 = tanh(agg(W0[z]) + b0), HALF-WAVE per node ----------------
// W0 is 64KB (L1/L2-hot) -> agg0 is latency-bound, so halving wave iterations
// (2 nodes/wave, float4 lanes) should cut time, unlike the BW-bound agg.
__global__ __launch_bounds__(256) void agg0_kernel(
    const int* __restrict__ z, const int* __restrict__ offsets,
    const int* __restrict__ csr_src, const float* __restrict__ dis,
    const float* __restrict__ W0, const float* __restrict__ b0,
    float* __restrict__ x1, int N) {
  int hw = (blockIdx.x * blockDim.x + threadIdx.x) >> 5;
  int lane = threadIdx.x & 31;
  if (hw >= N) return;
  int i = hw;
  int c0 = lane * 4;
  float di = dis[i];
  int beg = offsets[i], end = offsets[i + 1];
  float ax = 0.f, ay = 0.f, az = 0.f, aw = 0.f;
  int e = beg;
  for (; e + 8 <= end; e += 8) {
    int s0 = csr_src[e],     s1 = csr_src[e + 1], s2 = csr_src[e + 2], s3 = csr_src[e + 3];
    int s4 = csr_src[e + 4], s5 = csr_src[e + 5], s6 = csr_src[e + 6], s7 = csr_src[e + 7];
    float w0 = dis[s0], w1 = dis[s1], w2 = dis[s2], w3 = dis[s3];
    float w4 = dis[s4], w5 = dis[s5], w6 = dis[s6], w7 = dis[s7];
    const float4 y0 = *(const float4*)(W0 + (size_t)z[s0] * HD + c0);
    const float4 y1 = *(const float4*)(W0 + (size_t)z[s1] * HD + c0);
    const float4 y2 = *(const float4*)(W0 + (size_t)z[s2] * HD + c0);
    const float4 y3 = *(const float4*)(W0 + (size_t)z[s3] * HD + c0);
    const float4 y4 = *(const float4*)(W0 + (size_t)z[s4] * HD + c0);
    const float4 y5 = *(const float4*)(W0 + (size_t)z[s5] * HD + c0);
    const float4 y6 = *(const float4*)(W0 + (size_t)z[s6] * HD + c0);
    const float4 y7 = *(const float4*)(W0 + (size_t)z[s7] * HD + c0);
    ax = fmaf(w0, y0.x, fmaf(w1, y1.x, fmaf(w2, y2.x, fmaf(w3, y3.x, ax))));
    ay = fmaf(w0, y0.y, fmaf(w1, y1.y, fmaf(w2, y2.y, fmaf(w3, y3.y, ay))));
    az = fmaf(w0, y0.z, fmaf(w1, y1.z, fmaf(w2, y2.z, fmaf(w3, y3.z, az))));
    aw = fmaf(w0, y0.w, fmaf(w1, y1.w, fmaf(w2, y2.w, fmaf(w3, y3.w, aw))));
    ax = fmaf(w4, y4.x, fmaf(w5, y5.x, fmaf(w6, y6.x, fmaf(w7, y7.x, ax))));
    ay = fmaf(w4, y4.y, fmaf(w5, y5.y, fmaf(w6, y6.y, fmaf(w7, y7.y, ay))));
    az = fmaf(w4, y4.z, fmaf(w5, y5.z, fmaf(w6, y6.z, fmaf(w7, y7.z, az))));
    aw = fmaf(w4, y4.w, fmaf(w5, y5.w, fmaf(w6, y6.w, fmaf(w7, y7.w, aw))));
  }
  for (; e + 4 <= end; e += 4) {
    int s0 = csr_src[e], s1 = csr_src[e + 1], s2 = csr_src[e + 2], s3 = csr_src[e + 3];
    float w0 = dis[s0], w1 = dis[s1], w2 = dis[s2], w3 = dis[s3];
    const float4 y0 = *(const float4*)(W0 + (size_t)z[s0] * HD + c0);
    const float4 y1 = *(const float4*)(W0 + (size_t)z[s1] * HD + c0);
    const float4 y2 = *(const float4*)(W0 + (size_t)z[s2] * HD + c0);
    const float4 y3 = *(const float4*)(W0 + (size_t)z[s3] * HD + c0);
    ax = fmaf(w0, y0.x, fmaf(w1, y1.x, fmaf(w2, y2.x, fmaf(w3, y3.x, ax))));
    ay = fmaf(w0, y0.y, fmaf(w1, y1.y, fmaf(w2, y2.y, fmaf(w3, y3.y, ay))));
    az = fmaf(w0, y0.z, fmaf(w1, y1.z, fmaf(w2, y2.z, fmaf(w3, y3.z, az))));
    aw = fmaf(w0, y0.w, fmaf(w1, y1.w, fmaf(w2, y2.w, fmaf(w3, y3.w, aw))));
  }
  for (; e < end; ++e) {
    int s = csr_src[e];
    float w = dis[s];
    const float4 ys = *(const float4*)(W0 + (size_t)z[s] * HD + c0);
    ax = fmaf(w, ys.x, ax);
    ay = fmaf(w, ys.y, ay);
    az = fmaf(w, ys.z, az);
    aw = fmaf(w, ys.w, aw);
  }
  const float4 yi = *(const float4*)(W0 + (size_t)z[i] * HD + c0);
  const float4 bb = *(const float4*)(b0 + c0);
  float inv = di * di;  // norm of the self-loop exactly
  float4 o = make_float4(tanhf(di * ax + inv * yi.x + bb.x),
                         tanhf(di * ay + inv * yi.y + bb.y),
                         tanhf(di * az + inv * yi.z + bb.z),
                         tanhf(di * aw + inv * yi.w + bb.w));
  *(float4*)(x1 + (size_t)i * HD + c0) = o;
}

// ---------------- pure aggregation, HALF-WAVE per node (proven BW-ceiling config) ----------------
__global__ __launch_bounds__(256) void agg_kernel(
    const float* __restrict__ x, const int* __restrict__ offsets,
    const int* __restrict__ csr_src, const float* __restrict__ dis,
    float* __restrict__ T, int N) {
  int hw = (blockIdx.x * blockDim.x + threadIdx.x) >> 5;   // half-wave id = node id
  int lane = threadIdx.x & 31;
  if (hw >= N) return;
  int i = hw;
  int c0 = lane * 4;
  float di = dis[i];
  int beg = offsets[i], end = offsets[i + 1];
  float ax = 0.f, ay = 0.f, az = 0.f, aw = 0.f;
  int e = beg;
  for (; e + 8 <= end; e += 8) {                 // 8 float4 row-gathers in flight
    int s0 = csr_src[e],     s1 = csr_src[e + 1], s2 = csr_src[e + 2], s3 = csr_src[e + 3];
    int s4 = csr_src[e + 4], s5 = csr_src[e + 5], s6 = csr_src[e + 6], s7 = csr_src[e + 7];
    float w0 = dis[s0], w1 = dis[s1], w2 = dis[s2], w3 = dis[s3];
    float w4 = dis[s4], w5 = dis[s5], w6 = dis[s6], w7 = dis[s7];
    const float4 y0 = *(const float4*)(x + (size_t)s0 * HD + c0);
    const float4 y1 = *(const float4*)(x + (size_t)s1 * HD + c0);
    const float4 y2 = *(const float4*)(x + (size_t)s2 * HD + c0);
    const float4 y3 = *(const float4*)(x + (size_t)s3 * HD + c0);
    const float4 y4 = *(const float4*)(x + (size_t)s4 * HD + c0);
    const float4 y5 = *(const float4*)(x + (size_t)s5 * HD + c0);
    const float4 y6 = *(const float4*)(x + (size_t)s6 * HD + c0);
    const float4 y7 = *(const float4*)(x + (size_t)s7 * HD + c0);
    ax = fmaf(w0, y0.x, fmaf(w1, y1.x, fmaf(w2, y2.x, fmaf(w3, y3.x, ax))));
    ay = fmaf(w0, y0.y, fmaf(w1, y1.y, fmaf(w2, y2.y, fmaf(w3, y3.y, ay))));
    az = fmaf(w0, y0.z, fmaf(w1, y1.z, fmaf(w2, y2.z, fmaf(w3, y3.z, az))));
    aw = fmaf(w0, y0.w, fmaf(w1, y1.w, fmaf(w2, y2.w, fmaf(w3, y3.w, aw))));
    ax = fmaf(w4, y4.x, fmaf(w5, y5.x, fmaf(w6, y6.x, fmaf(w7, y7.x, ax))));
    ay = fmaf(w4, y4.y, fmaf(w5, y5.y, fmaf(w6, y6.y, fmaf(w7, y7.y, ay))));
    az = fmaf(w4, y4.z, fmaf(w5, y5.z, fmaf(w6, y6.z, fmaf(w7, y7.z, az))));
    aw = fmaf(w4, y4.w, fmaf(w5, y5.w, fmaf(w6, y6.w, fmaf(w7, y7.w, aw))));
  }
  for (; e + 4 <= end; e += 4) {
    int s0 = csr_src[e], s1 = csr_src[e + 1], s2 = csr_src[e + 2], s3 = csr_src[e + 3];
    float w0 = dis[s0], w1 = dis[s1], w2 = dis[s2], w3 = dis[s3];
    const float4 y0 = *(const float4*)(x + (size_t)s0 * HD + c0);
    const float4 y1 = *(const float4*)(x + (size_t)s1 * HD + c0);
    const float4 y2 = *(const float4*)(x + (size_t)s2 * HD + c0);
    const float4 y3 = *(const float4*)(x + (size_t)s3 * HD + c0);
    ax = fmaf(w0, y0.x, fmaf(w1, y1.x, fmaf(w2, y2.x, fmaf(w3, y3.x, ax))));
    ay = fmaf(w0, y0.y, fmaf(w1, y1.y, fmaf(w2, y2.y, fmaf(w3, y3.y, ay))));
    az = fmaf(w0, y0.z, fmaf(w1, y1.z, fmaf(w2, y2.z, fmaf(w3, y3.z, az))));
    aw = fmaf(w0, y0.w, fmaf(w1, y1.w, fmaf(w2, y2.w, fmaf(w3, y3.w, aw))));
  }
  for (; e < end; ++e) {
    int s = csr_src[e];
    float w = dis[s];
    const float4 ys = *(const float4*)(x + (size_t)s * HD + c0);
    ax = fmaf(w, ys.x, ax);
    ay = fmaf(w, ys.y, ay);
    az = fmaf(w, ys.z, az);
    aw = fmaf(w, ys.w, aw);
  }
  const float4 xi = *(const float4*)(x + (size_t)i * HD + c0);
  float inv = di * di;
  float4 o = make_float4(di * ax + inv * xi.x, di * ay + inv * xi.y,
                         di * az + inv * xi.z, di * aw + inv * xi.w);
  *(float4*)(T + (size_t)i * HD + c0) = o;
}

// ---------------- in-place f32 GEMM: T = tanh(T @ W + b), T[N,128], W[128,128] ----------------
// v3: 512 threads/block, 4x8 acc/thread (same 128x128 tile). Halves VGPR/thread,
// 8 waves/block, LDS 33KB -> 4 blocks/CU -> up to 32 waves/CU (4x the TLP of v1/v2)
// to hide LDS latency in the inner loop.
__global__ __launch_bounds__(512) void gemm_kernel(
    float* __restrict__ T, const float* __restrict__ W, const float* __restrict__ b, int N) {
  __shared__ float Xs[128][33];   // +1 pad; wave's 4 ty-rows hit 4 distinct banks (16-way bcast free)
  __shared__ float Ws[32][128];   // float4 reads at 16B lane stride
  int t = threadIdx.x;
  int r0 = blockIdx.x * 128;
  int ty = t >> 4, tx = t & 15;   // 32 x 16 thread grid
  int R0 = ty * 4;
  float acc[4][8];
#pragma unroll
  for (int a = 0; a < 4; ++a)
#pragma unroll
    for (int c = 0; c < 8; ++c) acc[a][c] = 0.f;

  for (int kb = 0; kb < 128; kb += 32) {
    __syncthreads();
    for (int l = t; l < 1024; l += 512) {       // 128 rows x 8 float4
      int r = l >> 3, c4 = (l & 7) << 2;
      float4 v = *(const float4*)(T + (size_t)(r0 + r) * HD + kb + c4);
      Xs[r][c4] = v.x; Xs[r][c4 + 1] = v.y; Xs[r][c4 + 2] = v.z; Xs[r][c4 + 3] = v.w;
    }
    for (int l = t; l < 1024; l += 512) {       // 32 rows x 32 float4
      int k = l >> 5, c4 = (l & 31) << 2;
      *(float4*)(&Ws[k][c4]) = *(const float4*)(W + (size_t)(kb + k) * HD + c4);
    }
    __syncthreads();
#pragma unroll
    for (int k = 0; k < 32; ++k) {
      float a[4];
#pragma unroll
      for (int ri = 0; ri < 4; ++ri) a[ri] = Xs[R0 + ri][k];
      float4 blo = *(const float4*)(&Ws[k][tx * 4]);
      float4 bhi = *(const float4*)(&Ws[k][64 + tx * 4]);
      float bb[8] = {blo.x, blo.y, blo.z, blo.w, bhi.x, bhi.y, bhi.z, bhi.w};
#pragma unroll
      for (int ri = 0; ri < 4; ++ri)
#pragma unroll
        for (int ci = 0; ci < 8; ++ci)
          acc[ri][ci] = fmaf(a[ri], bb[ci], acc[ri][ci]);
    }
  }
  float4 bl = *(const float4*)(b + tx * 4);
  float4 bh = *(const float4*)(b + 64 + tx * 4);
#pragma unroll
  for (int ri = 0; ri < 4; ++ri) {
    float4 o0 = make_float4(tanhf(acc[ri][0] + bl.x), tanhf(acc[ri][1] + bl.y),
                            tanhf(acc[ri][2] + bl.z), tanhf(acc[ri][3] + bl.w));
    float4 o1 = make_float4(tanhf(acc[ri][4] + bh.x), tanhf(acc[ri][5] + bh.y),
                            tanhf(acc[ri][6] + bh.z), tanhf(acc[ri][7] + bh.w));
    *(float4*)(T + (size_t)(r0 + R0 + ri) * HD + tx * 4) = o0;
    *(float4*)(T + (size_t)(r0 + R0 + ri) * HD + 64 + tx * 4) = o1;
  }
}

// ---------------- per-graph start offsets (batch is sorted) ----------------
__global__ void gstart_kernel(const int* __restrict__ batch, int* __restrict__ gstart,
                              int N, int B) {
  int g = blockIdx.x * blockDim.x + threadIdx.x;
  if (g > B) return;
  int lo = 0, hi = N;
  while (lo < hi) { int mid = (lo + hi) >> 1; if (batch[mid] < g) lo = mid + 1; else hi = mid; }
  gstart[g] = lo;
}

// ---------------- sort-pool + conv head, one block per graph, 512 threads ----------------
__global__ __launch_bounds__(512) void head_kernel(
    const float* __restrict__ X1, const float* __restrict__ X2, const float* __restrict__ X3,
    const int* __restrict__ gstart,
    const float* __restrict__ Wc1, const float* __restrict__ bc1,
    const float* __restrict__ Wc2, const float* __restrict__ bc2,
    const float* __restrict__ g1, const float* __restrict__ be1,
    const float* __restrict__ g2, const float* __restrict__ be2,
    const float* __restrict__ rm1, const float* __restrict__ rv1,
    const float* __restrict__ rm2, const float* __restrict__ rv2,
    const float* __restrict__ Wl1, const float* __restrict__ bl1,
    const float* __restrict__ Wl2, const float* __restrict__ bl2,
    float* __restrict__ out) {
  constexpr int MAXC = 512;    // >30 sigma above mean graph size of 128
  __shared__ float vals[MAXC];
  __shared__ int   sel[KK];
  __shared__ float ph[KK][385];          // 46200 B; region reused after conv1
  __shared__ float h1b[C1N][KK + 1];     // persists conv1 -> conv2
  // overlay into ph's region once ph is dead (after conv1):
  float* h2b  = &ph[0][0];               // [C2N * CONVL] = 832
  float* pp   = &ph[0][0] + 832;         // [FLAT] = 416
  float* part = &ph[0][0] + 1248;        // [512]
  float* l1v  = &ph[0][0] + 1760;        // [128]

  int g = blockIdx.x, t = threadIdx.x;
  int start = gstart[g];
  int count = gstart[g + 1] - start;
  if (count > MAXC) count = MAXC;
  int kk = count < KK ? count : KK;

  // ---- selection by parallel rank counting ----
  for (int i = t; i < count; i += 512)
    vals[i] = X3[(size_t)(start + i) * HD + (HD - 1)];
  __syncthreads();
  if (t < count) {
    float vi = vals[t];
    int rank = 0;
    for (int j = 0; j < count; ++j) {
      float vj = vals[j];
      rank += (vj > vi) || (vj == vi && j < t);
    }
    if (rank < KK) sel[rank] = t;
  }
  __syncthreads();

  // gather pooled rows from the three layer buffers (zero-pad short graphs)
  for (int l = t; l < KK * DD; l += 512) {
    int r = l / DD, d = l - r * DD;
    float v = 0.f;
    if (r < kk) {
      size_t n = (size_t)(start + sel[r]);
      v = (d < HD) ? X1[n * HD + d]
        : (d < 2 * HD) ? X2[n * HD + (d - HD)]
                       : X3[n * HD + (d - 2 * HD)];
    }
    ph[r][d] = v;
  }
  __syncthreads();

  // conv1 (kernel=stride=D) + relu + bn1   (480 items, one per thread)
  if (t < C1N * KK) {
    int c = t / KK, k = t - c * KK;
    const float* w = Wc1 + c * DD;
    float s = bc1[c];
    for (int d = 0; d < DD; ++d) s = fmaf(ph[k][d], w[d], s);
    s = fmaxf(s, 0.f);
    float sc = g1[c] * rsqrtf(rv1[c] + 1e-5f);
    h1b[c][k] = (s - rm1[c]) * sc + be1[c];
  }
  __syncthreads();   // conv1 reads of ph complete; ph region reusable below

  // conv2 (kernel 5, valid) + relu + bn2   (832 items)
  for (int l = t; l < C2N * CONVL; l += 512) {
    int o = l / CONVL, tt = l - o * CONVL;
    float s = bc2[o];
    const float* w = Wc2 + o * (C1N * KERN5);
#pragma unroll
    for (int c = 0; c < C1N; ++c)
#pragma unroll
      for (int q = 0; q < KERN5; ++q)
        s = fmaf(h1b[c][tt + q], w[c * KERN5 + q], s);
    s = fmaxf(s, 0.f);
    float sc = g2[o] * rsqrtf(rv2[o] + 1e-5f);
    h2b[o * CONVL + tt] = (s - rm2[o]) * sc + be2[o];
  }
  __syncthreads();

  // maxpool(2,2) + flatten (o-major)
  if (t < FLAT) {
    int o = t / PL, u = t - o * PL;
    pp[t] = fmaxf(h2b[o * CONVL + 2 * u], h2b[o * CONVL + 2 * u + 1]);
  }
  __syncthreads();

  // lin1 + relu, split each 416-dot across 4 threads
  {
    int j = t & 127, h = t >> 7;                 // h in {0..3}
    const int Q = FLAT / 4;                      // 104
    const float* w = Wl1 + (size_t)j * FLAT + h * Q;
    float s = (h == 0) ? bl1[j] : 0.f;
    for (int f = 0; f < Q; ++f) s = fmaf(pp[h * Q + f], w[f], s);
    part[t] = s;
  }
  __syncthreads();
  if (t < 128) l1v[t] = fmaxf(part[t] + part[t + 128] + part[t + 256] + part[t + 384], 0.f);
  __syncthreads();

  // lin2 -> scalar
  if (t < 64) {
    float s = l1v[t] * Wl2[t] + l1v[t + 64] * Wl2[t + 64];
#pragma unroll
    for (int o2 = 32; o2 > 0; o2 >>= 1) s += __shfl_down(s, o2);
    if (t == 0) out[g] = s + bl2[0];
  }
}

extern "C" void kernel_launch(void* const* d_in, const int* in_sizes, int n_in,
                              void* d_out, int out_size, void* d_ws, size_t ws_size,
                              hipStream_t stream) {
  const int*   z    = (const int*)d_in[0];
  const int*   ei   = (const int*)d_in[1];
  const int*   batch= (const int*)d_in[2];
  const float* W0   = (const float*)d_in[3];
  const float* b0   = (const float*)d_in[4];
  const float* W1   = (const float*)d_in[5];
  const float* b1   = (const float*)d_in[6];
  const float* W2   = (const float*)d_in[7];
  const float* b2   = (const float*)d_in[8];
  const float* Wc1  = (const float*)d_in[9];
  const float* bc1  = (const float*)d_in[10];
  const float* Wc2  = (const float*)d_in[11];
  const float* bc2  = (const float*)d_in[12];
  const float* g1   = (const float*)d_in[13];
  const float* be1  = (const float*)d_in[14];
  const float* g2   = (const float*)d_in[15];
  const float* be2  = (const float*)d_in[16];
  const float* Wl1  = (const float*)d_in[17];
  const float* bl1  = (const float*)d_in[18];
  const float* Wl2  = (const float*)d_in[19];
  const float* bl2  = (const float*)d_in[20];
  const float* rm1  = (const float*)d_in[21];
  const float* rv1  = (const float*)d_in[22];
  const float* rm2  = (const float*)d_in[23];
  const float* rv2  = (const float*)d_in[24];

  const int N = in_sizes[0];
  const int E = in_sizes[1] / 2;
  const int B = out_size;
  const int* rowp = ei;       // edge_index[0] = source
  const int* colp = ei + E;   // edge_index[1] = target (aggregation axis)

  // workspace plan: 3x64MB layer buffers + csr 4MB + ~2MB aux  (~198 MiB total)
  char* base = (char*)d_ws;
  size_t off = 0;
  auto alloc = [&](size_t bytes) -> void* {
    void* p = base + off;
    off += (bytes + 255) & ~(size_t)255;
    return p;
  };
  int*   cnt     = (int*)alloc((size_t)N * 4);
  int*   offsets = (int*)alloc(((size_t)N + 1) * 4);
  int*   cursor  = (int*)alloc((size_t)N * 4);
  int*   csr_src = (int*)alloc((size_t)E * 4);
  float* dis     = (float*)alloc((size_t)N * 4);
  int*   gstart  = (int*)alloc(((size_t)B + 1) * 4);
  int*   bsum    = (int*)alloc(1024 * 4);
  float* X1      = (float*)alloc((size_t)N * HD * 4);
  float* X2      = (float*)alloc((size_t)N * HD * 4);
  float* X3      = (float*)alloc((size_t)N * HD * 4);
  (void)ws_size; (void)n_in;

  hipMemsetAsync(cnt, 0, (size_t)N * 4, stream);
  hipMemsetAsync(cursor, 0, (size_t)N * 4, stream);

  const int nb = (N + 1023) / 1024;              // 128 for N=131072 (max 1024)
  deg_kernel<<<(E + 255) / 256, 256, 0, stream>>>(colp, cnt, E);
  scan1_kernel<<<nb, 256, 0, stream>>>(cnt, bsum, N);
  scan2_kernel<<<1, 1024, 0, stream>>>(bsum, nb);
  scan3_kernel<<<nb, 256, 0, stream>>>(cnt, bsum, offsets, dis, N);
  fill_kernel<<<(E + 255) / 256, 256, 0, stream>>>(rowp, colp, offsets, cursor, csr_src, E);

  // layer 0: onehot(z)@W0 == W0[z], fused into aggregation, tanh inside
  agg0_kernel<<<N / 8, 256, 0, stream>>>(z, offsets, csr_src, dis, W0, b0, X1, N);
  // layer 1: aggregate-first (half-wave gather), then in-place GEMM (+bias+tanh)
  agg_kernel<<<N / 8, 256, 0, stream>>>(X1, offsets, csr_src, dis, X2, N);
  gemm_kernel<<<N / 128, 512, 0, stream>>>(X2, W1, b1, N);
  // layer 2
  agg_kernel<<<N / 8, 256, 0, stream>>>(X2, offsets, csr_src, dis, X3, N);
  gemm_kernel<<<N / 128, 512, 0, stream>>>(X3, W2, b2, N);

  gstart_kernel<<<(B + 1 + 255) / 256, 256, 0, stream>>>(batch, gstart, N, B);
  head_kernel<<<B, 512, 0, stream>>>(X1, X2, X3, gstart, Wc1, bc1, Wc2, bc2, g1, be1, g2, be2,
                                     rm1, rv1, rm2, rv2, Wl1, bl1, Wl2, bl2, (float*)d_out);
}